// Round 10
// baseline (201.064 us; speedup 1.0000x reference)
//
#include <hip/hip_runtime.h>
#include <hip/hip_bf16.h>
#include <math.h>
#include <stdint.h>
#include <string.h>

#define BB 8
#define SS 96
#define DD 768
#define RR 24
#define RSEQ 8
#define TAG 3
#define D3 2304   // 3*D
#define NC 72     // R*TAG

typedef __attribute__((ext_vector_type(8))) short bf16x8;
typedef __attribute__((ext_vector_type(4))) float f32x4;
typedef _Float16 f16x8 __attribute__((ext_vector_type(8)));
typedef _Float16 f16x2 __attribute__((ext_vector_type(2)));

// async global->LDS, 16 B/lane; LDS dest = wave-uniform base + lane*16.
typedef __attribute__((address_space(3))) uint8_t lds_u8;
typedef const __attribute__((address_space(1))) uint8_t glb_u8;
static __device__ __forceinline__ void glld16(const void* g, void* l) {
  __builtin_amdgcn_global_load_lds((glb_u8*)g, (lds_u8*)l, 16, 0, 0);
}

#define VMW(N) asm volatile("s_waitcnt vmcnt(" #N ")" ::: "memory")

// round-half-up f32 pair -> packed bf16x2: add,add,v_perm = 3 VALU.
static __device__ inline uint32_t pkrhu(float lo, float hi) {
  uint32_t a, b;
  memcpy(&a, &lo, 4);
  memcpy(&b, &hi, 4);
  return __builtin_amdgcn_perm(b + 0x8000u, a + 0x8000u, 0x07060302u);
}
static __device__ inline uint32_t pkrne(float lo, float hi) {
  uint32_t a, b;
  memcpy(&a, &lo, 4);
  memcpy(&b, &hi, 4);
  a += 0x7FFFu + ((a >> 16) & 1u);
  b += 0x7FFFu + ((b >> 16) & 1u);
  return (a >> 16) | (b & 0xFFFF0000u);
}
// f32 pair -> packed f16x2 (v_cvt_f16_f32 x2 + pack)
static __device__ inline uint32_t pkf16(float lo, float hi) {
  union { f16x2 h; uint32_t u; } r;
  r.h[0] = (_Float16)lo;
  r.h[1] = (_Float16)hi;
  return r.u;
}
static __device__ inline uint16_t f16b(float v) {
  union { _Float16 h; uint16_t u; } r;
  r.h = (_Float16)v;
  return r.u;
}

// ---------------------------------------------------------------------------
// Kernel 0 (fused prep): blocks 0..35 = prepW (rel_W^T -> f16), 36..899 =
// proj_W transpose (bf16, feeds k_proj MFMA), 900..1027 = S0/G k-split
// partial dots (atomicAdd into pre-zeroed SG).
// ---------------------------------------------------------------------------
__global__ __launch_bounds__(256) void k_prep0(const float* __restrict__ relW,
                                               uint16_t* __restrict__ Wb,
                                               const float* __restrict__ projW,
                                               uint16_t* __restrict__ Tp,
                                               const float* __restrict__ enc,
                                               const float* __restrict__ rel,
                                               float* __restrict__ SG) {
  __shared__ __align__(16) char smem[24704];
  const int blk = blockIdx.x;
  const int t = threadIdx.x;

  if (blk < 36) {
    // ---- Wb[96][2304] f16 = rel_W^T (rows 72..79 zero; 80..95 untouched) ----
    float* tile = (float*)smem;  // 64*72 f32
    const int k0 = blk * 64;
    const float* src = relW + (size_t)k0 * NC;
    for (int e = t; e < 64 * NC / 4; e += 256) ((float4*)tile)[e] = ((const float4*)src)[e];
    __syncthreads();
    for (int u = t; u < 80 * 16; u += 256) {
      const int n = u >> 4, kq = (u & 15) * 4;
      uint2 w = {0u, 0u};
      if (n < NC) {
        w.x = pkf16(tile[(kq + 0) * NC + n], tile[(kq + 1) * NC + n]);
        w.y = pkf16(tile[(kq + 2) * NC + n], tile[(kq + 3) * NC + n]);
      }
      *(uint2*)&Wb[(size_t)n * D3 + k0 + kq] = w;
    }
  } else if (blk < 900) {
    // ---- Tp[2304][1536] bf16 = proj_W^T, 64x64 tile ----
    const int bx = blk - 36;
    float (*tile)[65] = (float(*)[65])smem;
    const int c0 = (bx % 36) * 64;
    const int r0 = (bx / 36) * 64;
    {
      const int tr = t >> 4;
      const int tc4 = (t & 15) * 4;
#pragma unroll
      for (int p = 0; p < 4; ++p) {
        const int r = tr + p * 16;
        const float4 v = *(const float4*)&projW[(size_t)(r0 + r) * D3 + c0 + tc4];
        tile[r][tc4 + 0] = v.x;
        tile[r][tc4 + 1] = v.y;
        tile[r][tc4 + 2] = v.z;
        tile[r][tc4 + 3] = v.w;
      }
    }
    __syncthreads();
    {
      const int cc = t >> 4;
      const int rr4 = (t & 15) * 4;
#pragma unroll
      for (int p = 0; p < 4; ++p) {
        const int c = cc + p * 16;
        uint2 w;
        w.x = pkrne(tile[rr4 + 0][c], tile[rr4 + 1][c]);
        w.y = pkrne(tile[rr4 + 2][c], tile[rr4 + 3][c]);
        *(uint2*)&Tp[(size_t)(c0 + c) * (2 * DD) + r0 + rr4] = w;
      }
    }
  } else {
    // ---- S0/G partial: sample b, d-chunk [d0, d0+48). ----
    const int idx = blk - 900;
    const int b = idx >> 4;
    const int d0 = (idx & 15) * 48;
    float (*AsF)[48] = (float(*)[48])smem;  // 8 x 48 f32 = 1.5 KB

    if (t < 96) {
      const int r = t / 12, q4 = (t % 12) * 4;
      *(float4*)&AsF[r][q4] = *(const float4*)&rel[((size_t)b * RSEQ + r) * DD + d0 + q4];
    }
    __syncthreads();

    for (int e = t; e < RSEQ * (SS + RSEQ); e += 256) {
      const int r = e & 7, s = e >> 3;
      const float* row = (s < SS) ? (enc + ((size_t)b * SS + s) * DD + d0) : &AsF[s - SS][0];
      float a0 = 0.f, a1 = 0.f, a2 = 0.f, a3 = 0.f;
#pragma unroll
      for (int d = 0; d < 48; d += 4) {
        const float4 rv = *(const float4*)&row[d];
        a0 += AsF[r][d + 0] * rv.x;
        a1 += AsF[r][d + 1] * rv.y;
        a2 += AsF[r][d + 2] * rv.z;
        a3 += AsF[r][d + 3] * rv.w;
      }
      atomicAdd(&SG[((size_t)b * RSEQ + r) * 104 + s], (a0 + a1) + (a2 + a3));
    }
  }
}

// ---------------------------------------------------------------------------
// Kernel 1a v3: refine serial core — barrier-free single wave per sample,
// JACOBI-correct: all 8 rows' softmax weights are computed from the
// previous-step P (stashed in w0/w1), and P is updated only after the row
// loop (matches the reference's scores-then-update semantics; v2's in-loop
// update was Gauss-Seidel and failed absmax). Lane l owns cols s=l and
// s=64+l (l<32); G[8][8] in registers. grid 8 x 64.
// ---------------------------------------------------------------------------
__global__ __launch_bounds__(64) void k_refS(const float* __restrict__ SG,
                                             float* __restrict__ Pst) {
  const int b = blockIdx.x;
  const int l = threadIdx.x;
  const float scale = 0.036084391824351613f;  // 1/sqrt(768)
  const float* base = SG + (size_t)b * RSEQ * 104;

  float g[RSEQ][RSEQ];
#pragma unroll
  for (int r = 0; r < RSEQ; ++r)
#pragma unroll
    for (int r2 = 0; r2 < RSEQ; ++r2) g[r][r2] = base[r * 104 + 96 + r2];

  float s0a[RSEQ], s0b[RSEQ], P0[RSEQ], P1[RSEQ];
#pragma unroll
  for (int r = 0; r < RSEQ; ++r) {
    s0a[r] = base[r * 104 + l];
    s0b[r] = (l < 32) ? base[r * 104 + 64 + l] : 0.f;
    P0[r] = 0.f;
    P1[r] = 0.f;
  }

  for (int step = 0; step < RR; ++step) {
    float w0[RSEQ], w1[RSEQ];
#pragma unroll
    for (int r = 0; r < RSEQ; ++r) {
      float a0 = s0a[r], a1 = s0b[r];
#pragma unroll
      for (int r2 = 0; r2 < RSEQ; ++r2) {
        a0 += g[r][r2] * P0[r2];
        a1 += g[r][r2] * P1[r2];
      }
      a0 *= scale;
      a1 *= scale;
      float mx = fmaxf(a0, (l < 32) ? a1 : -1e30f);
#pragma unroll
      for (int o = 32; o > 0; o >>= 1) mx = fmaxf(mx, __shfl_xor(mx, o, 64));
      const float e0 = __expf(a0 - mx);
      const float e1 = (l < 32) ? __expf(a1 - mx) : 0.f;
      float sm = e0 + e1;
#pragma unroll
      for (int o = 32; o > 0; o >>= 1) sm += __shfl_xor(sm, o, 64);
      const float inv = 1.f / sm;
      w0[r] = e0 * inv;
      w1[r] = e1 * inv;  // 0 for l >= 32
    }
    // Jacobi update: apply AFTER all rows' scores are computed.
#pragma unroll
    for (int r = 0; r < RSEQ; ++r) {
      P0[r] += w0[r];
      P1[r] += w1[r];
    }
  }

  float* pb = Pst + (size_t)b * RSEQ * SS;
#pragma unroll
  for (int r = 0; r < RSEQ; ++r) {
    pb[r * SS + l] = P0[r];
    if (l < 32) pb[r * SS + 64 + l] = P1[r];
  }
}

// ---------------------------------------------------------------------------
// Kernel 1b: refine epilogue: enc' bf16 = enc + P^T @ A. grid 96 (8 rows/blk).
// ---------------------------------------------------------------------------
__global__ __launch_bounds__(256) void k_refB(const float* __restrict__ enc,
                                              const float* __restrict__ rel,
                                              const float* __restrict__ Pst,
                                              uint16_t* __restrict__ encRb) {
  const int blk = blockIdx.x;
  const int b = blk / 12;
  const int s0 = (blk % 12) * 8;
  const int t = threadIdx.x;
  __shared__ float As[RSEQ][DD + 4];
  __shared__ float Pl[RSEQ][8];

  const float* Ag = rel + (size_t)b * RSEQ * DD;
  for (int e = t; e < RSEQ * DD / 4; e += 256) {
    const int r = (e * 4) / DD, d = (e * 4) % DD;
    *(float4*)&As[r][d] = *(const float4*)&Ag[e * 4];
  }
  if (t < RSEQ * 8) {
    const int r = t >> 3, sl = t & 7;
    Pl[r][sl] = Pst[(size_t)b * RSEQ * SS + r * SS + s0 + sl];
  }
  __syncthreads();

  const float* Eb = enc + ((size_t)b * SS + s0) * DD;
  uint16_t* Ob = encRb + ((size_t)b * SS + s0) * DD;
  for (int e = t; e < 8 * DD / 4; e += 256) {
    const int sl = (e * 4) / DD, d = (e * 4) % DD;
    float4 v = ((const float4*)Eb)[e];
#pragma unroll
    for (int r = 0; r < RSEQ; ++r) {
      const float p = Pl[r][sl];
      v.x += p * As[r][d + 0];
      v.y += p * As[r][d + 1];
      v.z += p * As[r][d + 2];
      v.w += p * As[r][d + 3];
    }
    uint2 w;
    w.x = pkrhu(v.x, v.y);
    w.y = pkrhu(v.z, v.w);
    *(uint2*)&Ob[e * 4] = w;
  }
}

// ---------------------------------------------------------------------------
// Kernel 2 v2: projection GEMM — 128x64 tiles (was 64x64): reads/MFMA 1.0 ->
// 0.75, total barrier-drains halve (432 blocks). Same glld16 2-barrier
// schedule. LDS 27648 B -> still 4 blocks/CU. grid (6,72).
// ---------------------------------------------------------------------------
__global__ __launch_bounds__(256, 4) void k_proj(const uint16_t* __restrict__ Ab,
                                                 const uint16_t* __restrict__ Bt,
                                                 const float* __restrict__ pb,
                                                 uint16_t* __restrict__ Hh16,
                                                 uint16_t* __restrict__ Htf) {
  const int m0 = blockIdx.x * 128;
  const int gn0 = blockIdx.y * 64;
  const bool isH = gn0 < D3;               // uniform per block
  const int n0 = isH ? gn0 : gn0 - D3;
  const int halfk = isH ? 0 : DD;
  const int t = threadIdx.x, w = t >> 6, lane = t & 63;
  const int wm = w >> 1, wn = w & 1;
  const int lm = lane & 15, q = lane >> 4;

  __shared__ __align__(16) uint16_t As[128 * 72];  // 18432 B (18 issues)
  __shared__ __align__(16) uint16_t Bs[64 * 72];   //  9216 B (9 issues)

  const char* rp[7];
  char* lp[7];
#pragma unroll
  for (int r = 0; r < 7; ++r) {
    const int idx = w + 4 * r;
    rp[r] = nullptr;
    lp[r] = nullptr;
    if (idx < 27) {
      const int ii = (idx < 18) ? idx : idx - 18;
      const int beta = ii * 1024 + lane * 16;
      const int elem = beta >> 1;
      const int row = elem / 72;
      int o = elem - row * 72;
      if (o >= 64) o = 0;  // pad lanes: safe addr, land in LDS row pad
      if (idx < 18) {
        rp[r] = (const char*)(Ab + (size_t)(m0 + row) * DD + o);
        lp[r] = (char*)As + ii * 1024;
      } else {
        rp[r] = (const char*)(Bt + (size_t)(n0 + row) * (2 * DD) + halfk + o);
        lp[r] = (char*)Bs + ii * 1024;
      }
    }
  }

  f32x4 acc[4][2];
#pragma unroll
  for (int a = 0; a < 4; ++a)
#pragma unroll
    for (int c = 0; c < 2; ++c) acc[a][c] = (f32x4){0.f, 0.f, 0.f, 0.f};

  for (int k0 = 0; k0 < DD; k0 += 64) {
    __syncthreads();
#pragma unroll
    for (int r = 0; r < 7; ++r)
      if (rp[r]) glld16(rp[r] + 2 * k0, lp[r]);
    __syncthreads();
#pragma unroll
    for (int kk = 0; kk < 2; ++kk) {
      const int ko = kk * 32 + q * 8;
      bf16x8 af[4], bf[2];
#pragma unroll
      for (int mt = 0; mt < 4; ++mt)
        af[mt] = *(const bf16x8*)&As[(wm * 64 + mt * 16 + lm) * 72 + ko];
#pragma unroll
      for (int nt = 0; nt < 2; ++nt)
        bf[nt] = *(const bf16x8*)&Bs[(wn * 32 + nt * 16 + lm) * 72 + ko];
#pragma unroll
      for (int nt = 0; nt < 2; ++nt)
#pragma unroll
        for (int mt = 0; mt < 4; ++mt)
          acc[mt][nt] = __builtin_amdgcn_mfma_f32_16x16x32_bf16(af[mt], bf[nt], acc[mt][nt], 0, 0, 0);
    }
  }

#pragma unroll
  for (int nt = 0; nt < 2; ++nt) {
    const int ncol = n0 + wn * 32 + nt * 16 + lm;
    const int mrow = m0 + wm * 64 + q * 4;
    uint16_t* dst = isH ? Hh16 : Htf;
    const float bias = isH ? pb[ncol] : 0.f;
#pragma unroll
    for (int mt = 0; mt < 4; ++mt)
#pragma unroll
      for (int r = 0; r < 4; ++r)
        dst[(size_t)(mrow + mt * 16 + r) * D3 + ncol] = f16b(acc[mt][nt][r] + bias);
  }
}

// ---------------------------------------------------------------------------
// Kernel 3: pairwise GEMM v14 (frozen) — 12 waves = (iw x jh x kh); wave does
// full 48x80 tile of its i for its K=64 half of each 128-K phase; wave pairs
// reduce acc at the end through dead Stg. 3 pair-bufs, issue-after-barrier,
// counted vmcnt 4/2, XOR-swizzle, wrap prefetch, LDS 150528 -> 1 block/CU.
// grid 256, 768 threads.
// ---------------------------------------------------------------------------
#define HT_LDS 12288                     // 96 rows x 128 B
#define CH_B 22528                       // one chunk: 22 issues x 1024
#define NISS 22
#define NKC 36                           // K chunks of 64
#define NPH 18                           // phases of 2 chunks

__global__ __launch_bounds__(768, 1) void k_pairs(const uint16_t* __restrict__ Hh,
                                                  const uint16_t* __restrict__ Htb,
                                                  const uint16_t* __restrict__ Wb,
                                                  const float* __restrict__ relb,
                                                  float* __restrict__ out) {
  const int blk = blockIdx.x;
  const int b = blk >> 5, ii = blk & 31;
  const int t = threadIdx.x;
  const int w = t >> 6, lane = t & 63;
  const int lm = lane & 15, q = lane >> 4;
  const int iw = w >> 2;            // which of the 3 i's
  const int jh = (w >> 1) & 1;      // j-half (48 rows)
  const int kh = w & 1;             // K-half of each phase
  const int i = ii * 3 + iw;

  __shared__ __align__(16) uint16_t Hr[7680];             // 15360 B
  __shared__ __align__(16) uint16_t Stg[3][CH_B];         // 3 pair-bufs x 45056 B

  // ---- one-time: stage the 3 Hh rows (linear; issue idx 13 runs 512 B past
  //      the 3 rows — covered by Hh's slack) ----
  {
    const char* hh = (const char*)(Hh + ((size_t)b * SS + ii * 3) * D3);
#pragma unroll
    for (int r = 0; r < 2; ++r) {
      const int idx = w + 12 * r;
      if (idx < 14) glld16(hh + idx * 1024 + lane * 16, (char*)Hr + idx * 1024);
    }
  }

  // ---- per-lane k0-invariant inverse-swizzled source pointers.
  //      LDS byte beta holds elem (real>>1) of its row, real = off^((row&7)<<4).
  //      Issues per wave per chunk: w0-9: 2, w10-11: 1.
  const char* rp[2];
#pragma unroll
  for (int r = 0; r < 2; ++r) {
    const int idx = w + 12 * r;
    rp[r] = nullptr;
    if (idx < NISS) {
      const int beta = idx * 1024 + lane * 16;
      if (beta < HT_LDS) {
        const int row = beta >> 7;
        const int real = (beta & 127) ^ ((row & 7) << 4);
        rp[r] = (const char*)(Htb + ((size_t)b * SS + row) * D3 + (real >> 1));
      } else {
        const int bb = beta - HT_LDS;
        const int row = bb >> 7;
        const int real = (bb & 127) ^ ((row & 7) << 4);
        rp[r] = (const char*)(Wb + (size_t)row * D3 + (real >> 1));
      }
    }
  }

  // ---- prologue: stage pairs 0 and 1 ----
#pragma unroll
  for (int pp = 0; pp < 2; ++pp)
#pragma unroll
    for (int kc = 0; kc < 2; ++kc)
#pragma unroll
      for (int r = 0; r < 2; ++r)
        if (rp[r])
          glld16(rp[r] + (size_t)128 * (2 * pp + kc),
                 (char*)Stg[pp] + kc * CH_B + (w + 12 * r) * 1024);

  f32x4 acc[3][5];
#pragma unroll
  for (int mt = 0; mt < 3; ++mt)
#pragma unroll
    for (int nt = 0; nt < 5; ++nt) acc[mt][nt] = (f32x4){0.f, 0.f, 0.f, 0.f};

  const f16x8 zro = {0, 0, 0, 0, 0, 0, 0, 0};

  for (int p = 0; p < NPH; ++p) {
    // drain pair-p loads (and Hr on phase 0); keep pair p+1 in flight.
    if (w < 10) VMW(4); else VMW(2);
    __builtin_amdgcn_s_barrier();   // all waves' pair-p loads visible
    __builtin_amdgcn_sched_barrier(0);

    // issue pair p+2 into buf[(p+2)%3] — overlaps this phase's compute.
    // Past the end it WRAPS (dead buffer, always-valid addrs, uniform vmcnt).
    {
      char* dst = (char*)Stg[(p + 2) % 3];
      int pn = p + 2;
      if (pn >= NPH) pn -= NPH;
#pragma unroll
      for (int kc = 0; kc < 2; ++kc)
#pragma unroll
        for (int r = 0; r < 2; ++r)
          if (rp[r])
            glld16(rp[r] + (size_t)128 * (2 * pn + kc),
                   dst + kc * CH_B + (w + 12 * r) * 1024);
    }

    // this wave computes only its K-half (kh) of the 128-K phase.
    const char* S = (const char*)Stg[p % 3] + kh * CH_B;
    const int k0 = (2 * p + kh) * 64;
#pragma unroll
    for (int kk = 0; kk < 2; ++kk) {
      const int ko = kk * 32 + q * 8;
      const int xb = (ko * 2) ^ ((lane & 7) << 4);  // swizzled byte off
      const f16x8 hv = *(const f16x8*)&Hr[iw * D3 + k0 + ko];
      f16x8 af[3];
#pragma unroll
      for (int mt = 0; mt < 3; ++mt) {
        const f16x8 s = *(const f16x8*)(S + (jh * 48 + mt * 16 + lm) * 128 + xb) + hv;
        af[mt] = __builtin_elementwise_max(s, zro);
      }
      f16x8 bfv[5];
#pragma unroll
      for (int nt = 0; nt < 5; ++nt)
        bfv[nt] = *(const f16x8*)(S + HT_LDS + (nt * 16 + lm) * 128 + xb);
      __builtin_amdgcn_s_setprio(1);
#pragma unroll
      for (int nt = 0; nt < 5; ++nt)
#pragma unroll
        for (int mt = 0; mt < 3; ++mt)
          acc[mt][nt] = __builtin_amdgcn_mfma_f32_16x16x32_f16(af[mt], bfv[nt], acc[mt][nt], 0, 0, 0);
      __builtin_amdgcn_s_setprio(0);
    }
    // retire all own ds_reads before arriving at the next barrier, so the
    // DMA overwrite of buf[p%3] (issued after barrier p+1) cannot race them.
    asm volatile("s_waitcnt lgkmcnt(0)" ::: "memory");
    __builtin_amdgcn_sched_barrier(0);
  }

  // ---- cross-wave kh reduction through the (now dead) Stg LDS. ----
  // __syncthreads drains this wave's DMAs (incl. wrap prefetches) and
  // barriers, so no stale glld16 can land in Stg after this point.
  __syncthreads();
  float* RED = (float*)&Stg[0][0];  // 6 pairs x 15 slots x 1024 B = 92160 B
  if (w & 1) {
#pragma unroll
    for (int mt = 0; mt < 3; ++mt)
#pragma unroll
      for (int nt = 0; nt < 5; ++nt)
        *(f32x4*)&RED[(((w >> 1) * 15 + mt * 5 + nt) << 8) + lane * 4] = acc[mt][nt];
  }
  __syncthreads();
  if (!(w & 1)) {
    // epilogue: C layout col=lm (c), row=q*4+r (j within 16-tile)
#pragma unroll
    for (int nt = 0; nt < 5; ++nt) {
      const int c = nt * 16 + lm;
      if (c < NC) {
        const float rb = relb[c];
        const int rr = c / 3, tg = c % 3;
#pragma unroll
        for (int mt = 0; mt < 3; ++mt) {
          const f32x4 oth = *(const f32x4*)&RED[(((w >> 1) * 15 + mt * 5 + nt) << 8) + lane * 4];
          const int j0 = jh * 48 + mt * 16 + q * 4;
          float* base = out + ((((size_t)b * TAG + tg) * RR + rr) * SS + i) * SS + j0;
          float4 o;
          o.x = acc[mt][nt][0] + oth[0] + rb;
          o.y = acc[mt][nt][1] + oth[1] + rb;
          o.z = acc[mt][nt][2] + oth[2] + rb;
          o.w = acc[mt][nt][3] + oth[3] + rb;
          *(float4*)base = o;
        }
      }
    }
  }
}

// ---------------------------------------------------------------------------
extern "C" void kernel_launch(void* const* d_in, const int* in_sizes, int n_in,
                              void* d_out, int out_size, void* d_ws, size_t ws_size,
                              hipStream_t stream) {
  const float* enc   = (const float*)d_in[0];  // [8,96,768]
  const float* rel   = (const float*)d_in[1];  // [24,8,768]
  const float* projW = (const float*)d_in[2];  // [1536,2304]
  const float* projb = (const float*)d_in[3];  // [2304]
  const float* relW  = (const float*)d_in[4];  // [2304,72]
  const float* relb  = (const float*)d_in[5];  // [72]
  float* out = (float*)d_out;                  // [8,3,24,96,96]

  uint16_t* Hh16 = (uint16_t*)d_ws;                       // 768*2304 f16 (+512 slack)
  uint16_t* Htf  = Hh16 + (size_t)DD * D3 + 512;          // 768*2304 f16
  uint16_t* Wb   = Htf + (size_t)DD * D3;                 // 96*2304 f16 (80 used)
  uint16_t* Tp   = Wb + (size_t)96 * D3;                  // 2304*1536 bf16
  uint16_t* Ab   = Tp + (size_t)D3 * 2 * DD;              // 768*768 bf16
  float* Pst = (float*)(Ab + (size_t)DD * DD);            // 8*8*96 f32
  float* SG = Pst + (size_t)BB * RSEQ * SS;               // 8*8*104 f32

  hipMemsetAsync(SG, 0, (size_t)BB * RSEQ * 104 * sizeof(float), stream);
  k_prep0<<<1028, 256, 0, stream>>>(relW, Wb, projW, Tp, enc, rel, SG);
  k_refS<<<BB, 64, 0, stream>>>(SG, Pst);
  k_refB<<<96, 256, 0, stream>>>(enc, rel, Pst, Ab);
  k_proj<<<dim3(6, 72), 256, 0, stream>>>(Ab, Tp, projb, Hh16, Htf);
  k_pairs<<<256, 768, 0, stream>>>(Hh16, Htf, Wb, relb, out);
}

// Round 11
// 200.935 us; speedup vs baseline: 1.0006x; 1.0006x over previous
//
#include <hip/hip_runtime.h>
#include <hip/hip_bf16.h>
#include <math.h>
#include <stdint.h>
#include <string.h>

#define BB 8
#define SS 96
#define DD 768
#define RR 24
#define RSEQ 8
#define TAG 3
#define D3 2304   // 3*D
#define NC 72     // R*TAG

typedef __attribute__((ext_vector_type(8))) short bf16x8;
typedef __attribute__((ext_vector_type(4))) float f32x4;
typedef _Float16 f16x8 __attribute__((ext_vector_type(8)));
typedef _Float16 f16x2 __attribute__((ext_vector_type(2)));

// async global->LDS, 16 B/lane; LDS dest = wave-uniform base + lane*16.
typedef __attribute__((address_space(3))) uint8_t lds_u8;
typedef const __attribute__((address_space(1))) uint8_t glb_u8;
static __device__ __forceinline__ void glld16(const void* g, void* l) {
  __builtin_amdgcn_global_load_lds((glb_u8*)g, (lds_u8*)l, 16, 0, 0);
}

#define VMW(N) asm volatile("s_waitcnt vmcnt(" #N ")" ::: "memory")

// round-half-up f32 pair -> packed bf16x2: add,add,v_perm = 3 VALU.
static __device__ inline uint32_t pkrhu(float lo, float hi) {
  uint32_t a, b;
  memcpy(&a, &lo, 4);
  memcpy(&b, &hi, 4);
  return __builtin_amdgcn_perm(b + 0x8000u, a + 0x8000u, 0x07060302u);
}
static __device__ inline uint32_t pkrne(float lo, float hi) {
  uint32_t a, b;
  memcpy(&a, &lo, 4);
  memcpy(&b, &hi, 4);
  a += 0x7FFFu + ((a >> 16) & 1u);
  b += 0x7FFFu + ((b >> 16) & 1u);
  return (a >> 16) | (b & 0xFFFF0000u);
}
// f32 pair -> packed f16x2 (v_cvt_f16_f32 x2 + pack)
static __device__ inline uint32_t pkf16(float lo, float hi) {
  union { f16x2 h; uint32_t u; } r;
  r.h[0] = (_Float16)lo;
  r.h[1] = (_Float16)hi;
  return r.u;
}
static __device__ inline uint16_t f16b(float v) {
  union { _Float16 h; uint16_t u; } r;
  r.h = (_Float16)v;
  return r.u;
}

// ---------------------------------------------------------------------------
// Kernel 0 (fused prep): blocks 0..35 = prepW (rel_W^T -> f16), 36..899 =
// proj_W transpose (bf16, feeds k_proj MFMA), 900..1027 = S0/G k-split
// partial dots (atomicAdd into pre-zeroed SG).
// ---------------------------------------------------------------------------
__global__ __launch_bounds__(256) void k_prep0(const float* __restrict__ relW,
                                               uint16_t* __restrict__ Wb,
                                               const float* __restrict__ projW,
                                               uint16_t* __restrict__ Tp,
                                               const float* __restrict__ enc,
                                               const float* __restrict__ rel,
                                               float* __restrict__ SG) {
  __shared__ __align__(16) char smem[24704];
  const int blk = blockIdx.x;
  const int t = threadIdx.x;

  if (blk < 36) {
    // ---- Wb[96][2304] f16 = rel_W^T (rows 72..79 zero; 80..95 untouched) ----
    float* tile = (float*)smem;  // 64*72 f32
    const int k0 = blk * 64;
    const float* src = relW + (size_t)k0 * NC;
    for (int e = t; e < 64 * NC / 4; e += 256) ((float4*)tile)[e] = ((const float4*)src)[e];
    __syncthreads();
    for (int u = t; u < 80 * 16; u += 256) {
      const int n = u >> 4, kq = (u & 15) * 4;
      uint2 w = {0u, 0u};
      if (n < NC) {
        w.x = pkf16(tile[(kq + 0) * NC + n], tile[(kq + 1) * NC + n]);
        w.y = pkf16(tile[(kq + 2) * NC + n], tile[(kq + 3) * NC + n]);
      }
      *(uint2*)&Wb[(size_t)n * D3 + k0 + kq] = w;
    }
  } else if (blk < 900) {
    // ---- Tp[2304][1536] bf16 = proj_W^T, 64x64 tile ----
    const int bx = blk - 36;
    float (*tile)[65] = (float(*)[65])smem;
    const int c0 = (bx % 36) * 64;
    const int r0 = (bx / 36) * 64;
    {
      const int tr = t >> 4;
      const int tc4 = (t & 15) * 4;
#pragma unroll
      for (int p = 0; p < 4; ++p) {
        const int r = tr + p * 16;
        const float4 v = *(const float4*)&projW[(size_t)(r0 + r) * D3 + c0 + tc4];
        tile[r][tc4 + 0] = v.x;
        tile[r][tc4 + 1] = v.y;
        tile[r][tc4 + 2] = v.z;
        tile[r][tc4 + 3] = v.w;
      }
    }
    __syncthreads();
    {
      const int cc = t >> 4;
      const int rr4 = (t & 15) * 4;
#pragma unroll
      for (int p = 0; p < 4; ++p) {
        const int c = cc + p * 16;
        uint2 w;
        w.x = pkrne(tile[rr4 + 0][c], tile[rr4 + 1][c]);
        w.y = pkrne(tile[rr4 + 2][c], tile[rr4 + 3][c]);
        *(uint2*)&Tp[(size_t)(c0 + c) * (2 * DD) + r0 + rr4] = w;
      }
    }
  } else {
    // ---- S0/G partial: sample b, d-chunk [d0, d0+48). ----
    const int idx = blk - 900;
    const int b = idx >> 4;
    const int d0 = (idx & 15) * 48;
    float (*AsF)[48] = (float(*)[48])smem;  // 8 x 48 f32 = 1.5 KB

    if (t < 96) {
      const int r = t / 12, q4 = (t % 12) * 4;
      *(float4*)&AsF[r][q4] = *(const float4*)&rel[((size_t)b * RSEQ + r) * DD + d0 + q4];
    }
    __syncthreads();

    for (int e = t; e < RSEQ * (SS + RSEQ); e += 256) {
      const int r = e & 7, s = e >> 3;
      const float* row = (s < SS) ? (enc + ((size_t)b * SS + s) * DD + d0) : &AsF[s - SS][0];
      float a0 = 0.f, a1 = 0.f, a2 = 0.f, a3 = 0.f;
#pragma unroll
      for (int d = 0; d < 48; d += 4) {
        const float4 rv = *(const float4*)&row[d];
        a0 += AsF[r][d + 0] * rv.x;
        a1 += AsF[r][d + 1] * rv.y;
        a2 += AsF[r][d + 2] * rv.z;
        a3 += AsF[r][d + 3] * rv.w;
      }
      atomicAdd(&SG[((size_t)b * RSEQ + r) * 104 + s], (a0 + a1) + (a2 + a3));
    }
  }
}

// ---------------------------------------------------------------------------
// Kernel 1a v4: refine serial core — barrier-free single wave per sample,
// Jacobi-correct, with EXPLICIT 8-ROW ILP: all 8 rows' scores computed first,
// then the shuffle-reduce trees run LEVEL-BY-LEVEL across all rows so the 8
// ds_bpermute ops per level pipeline (v3 ran rows serially: 12 dependent
// ~60cy bpermutes per row = 760 cy/row -> 60 us). Per-row xor order
// (32,16,8,4,2,1) unchanged -> bit-identical results. grid 8 x 64.
// ---------------------------------------------------------------------------
__global__ __launch_bounds__(64) void k_refS(const float* __restrict__ SG,
                                             float* __restrict__ Pst) {
  const int b = blockIdx.x;
  const int l = threadIdx.x;
  const float scale = 0.036084391824351613f;  // 1/sqrt(768)
  const float* base = SG + (size_t)b * RSEQ * 104;

  float g[RSEQ][RSEQ];
#pragma unroll
  for (int r = 0; r < RSEQ; ++r)
#pragma unroll
    for (int r2 = 0; r2 < RSEQ; ++r2) g[r][r2] = base[r * 104 + 96 + r2];

  float s0a[RSEQ], s0b[RSEQ], P0[RSEQ], P1[RSEQ];
#pragma unroll
  for (int r = 0; r < RSEQ; ++r) {
    s0a[r] = base[r * 104 + l];
    s0b[r] = (l < 32) ? base[r * 104 + 64 + l] : 0.f;
    P0[r] = 0.f;
    P1[r] = 0.f;
  }

  for (int step = 0; step < RR; ++step) {
    float a0[RSEQ], a1[RSEQ], mx[RSEQ];
    // 1) all 8 rows' scores (independent FMA chains — ILP)
#pragma unroll
    for (int r = 0; r < RSEQ; ++r) {
      float x0 = s0a[r], x1 = s0b[r];
#pragma unroll
      for (int r2 = 0; r2 < RSEQ; ++r2) {
        x0 += g[r][r2] * P0[r2];
        x1 += g[r][r2] * P1[r2];
      }
      a0[r] = x0 * scale;
      a1[r] = x1 * scale;
      mx[r] = fmaxf(a0[r], (l < 32) ? a1[r] : -1e30f);
    }
    // 2) max trees, level-major: 8 independent bpermutes per level pipeline
#pragma unroll
    for (int o = 32; o > 0; o >>= 1) {
      float sh[RSEQ];
#pragma unroll
      for (int r = 0; r < RSEQ; ++r) sh[r] = __shfl_xor(mx[r], o, 64);
#pragma unroll
      for (int r = 0; r < RSEQ; ++r) mx[r] = fmaxf(mx[r], sh[r]);
    }
    // 3) exps
    float e0[RSEQ], e1[RSEQ], sm[RSEQ];
#pragma unroll
    for (int r = 0; r < RSEQ; ++r) {
      e0[r] = __expf(a0[r] - mx[r]);
      e1[r] = (l < 32) ? __expf(a1[r] - mx[r]) : 0.f;
      sm[r] = e0[r] + e1[r];
    }
    // 4) sum trees, level-major
#pragma unroll
    for (int o = 32; o > 0; o >>= 1) {
      float sh[RSEQ];
#pragma unroll
      for (int r = 0; r < RSEQ; ++r) sh[r] = __shfl_xor(sm[r], o, 64);
#pragma unroll
      for (int r = 0; r < RSEQ; ++r) sm[r] += sh[r];
    }
    // 5) Jacobi update (after all rows' weights computed)
#pragma unroll
    for (int r = 0; r < RSEQ; ++r) {
      const float inv = 1.f / sm[r];
      P0[r] += e0[r] * inv;
      P1[r] += e1[r] * inv;  // 0 for l >= 32
    }
  }

  float* pb = Pst + (size_t)b * RSEQ * SS;
#pragma unroll
  for (int r = 0; r < RSEQ; ++r) {
    pb[r * SS + l] = P0[r];
    if (l < 32) pb[r * SS + 64 + l] = P1[r];
  }
}

// ---------------------------------------------------------------------------
// Kernel 1b: refine epilogue: enc' bf16 = enc + P^T @ A. grid 96 (8 rows/blk).
// ---------------------------------------------------------------------------
__global__ __launch_bounds__(256) void k_refB(const float* __restrict__ enc,
                                              const float* __restrict__ rel,
                                              const float* __restrict__ Pst,
                                              uint16_t* __restrict__ encRb) {
  const int blk = blockIdx.x;
  const int b = blk / 12;
  const int s0 = (blk % 12) * 8;
  const int t = threadIdx.x;
  __shared__ float As[RSEQ][DD + 4];
  __shared__ float Pl[RSEQ][8];

  const float* Ag = rel + (size_t)b * RSEQ * DD;
  for (int e = t; e < RSEQ * DD / 4; e += 256) {
    const int r = (e * 4) / DD, d = (e * 4) % DD;
    *(float4*)&As[r][d] = *(const float4*)&Ag[e * 4];
  }
  if (t < RSEQ * 8) {
    const int r = t >> 3, sl = t & 7;
    Pl[r][sl] = Pst[(size_t)b * RSEQ * SS + r * SS + s0 + sl];
  }
  __syncthreads();

  const float* Eb = enc + ((size_t)b * SS + s0) * DD;
  uint16_t* Ob = encRb + ((size_t)b * SS + s0) * DD;
  for (int e = t; e < 8 * DD / 4; e += 256) {
    const int sl = (e * 4) / DD, d = (e * 4) % DD;
    float4 v = ((const float4*)Eb)[e];
#pragma unroll
    for (int r = 0; r < RSEQ; ++r) {
      const float p = Pl[r][sl];
      v.x += p * As[r][d + 0];
      v.y += p * As[r][d + 1];
      v.z += p * As[r][d + 2];
      v.w += p * As[r][d + 3];
    }
    uint2 w;
    w.x = pkrhu(v.x, v.y);
    w.y = pkrhu(v.z, v.w);
    *(uint2*)&Ob[e * 4] = w;
  }
}

// ---------------------------------------------------------------------------
// Kernel 2 v2: projection GEMM — 128x64 tiles: reads/MFMA 0.75, 432 blocks.
// glld16 2-barrier schedule. LDS 27648 B -> 4 blocks/CU. grid (6,72).
// ---------------------------------------------------------------------------
__global__ __launch_bounds__(256, 4) void k_proj(const uint16_t* __restrict__ Ab,
                                                 const uint16_t* __restrict__ Bt,
                                                 const float* __restrict__ pb,
                                                 uint16_t* __restrict__ Hh16,
                                                 uint16_t* __restrict__ Htf) {
  const int m0 = blockIdx.x * 128;
  const int gn0 = blockIdx.y * 64;
  const bool isH = gn0 < D3;               // uniform per block
  const int n0 = isH ? gn0 : gn0 - D3;
  const int halfk = isH ? 0 : DD;
  const int t = threadIdx.x, w = t >> 6, lane = t & 63;
  const int wm = w >> 1, wn = w & 1;
  const int lm = lane & 15, q = lane >> 4;

  __shared__ __align__(16) uint16_t As[128 * 72];  // 18432 B (18 issues)
  __shared__ __align__(16) uint16_t Bs[64 * 72];   //  9216 B (9 issues)

  const char* rp[7];
  char* lp[7];
#pragma unroll
  for (int r = 0; r < 7; ++r) {
    const int idx = w + 4 * r;
    rp[r] = nullptr;
    lp[r] = nullptr;
    if (idx < 27) {
      const int ii = (idx < 18) ? idx : idx - 18;
      const int beta = ii * 1024 + lane * 16;
      const int elem = beta >> 1;
      const int row = elem / 72;
      int o = elem - row * 72;
      if (o >= 64) o = 0;  // pad lanes: safe addr, land in LDS row pad
      if (idx < 18) {
        rp[r] = (const char*)(Ab + (size_t)(m0 + row) * DD + o);
        lp[r] = (char*)As + ii * 1024;
      } else {
        rp[r] = (const char*)(Bt + (size_t)(n0 + row) * (2 * DD) + halfk + o);
        lp[r] = (char*)Bs + ii * 1024;
      }
    }
  }

  f32x4 acc[4][2];
#pragma unroll
  for (int a = 0; a < 4; ++a)
#pragma unroll
    for (int c = 0; c < 2; ++c) acc[a][c] = (f32x4){0.f, 0.f, 0.f, 0.f};

  for (int k0 = 0; k0 < DD; k0 += 64) {
    __syncthreads();
#pragma unroll
    for (int r = 0; r < 7; ++r)
      if (rp[r]) glld16(rp[r] + 2 * k0, lp[r]);
    __syncthreads();
#pragma unroll
    for (int kk = 0; kk < 2; ++kk) {
      const int ko = kk * 32 + q * 8;
      bf16x8 af[4], bf[2];
#pragma unroll
      for (int mt = 0; mt < 4; ++mt)
        af[mt] = *(const bf16x8*)&As[(wm * 64 + mt * 16 + lm) * 72 + ko];
#pragma unroll
      for (int nt = 0; nt < 2; ++nt)
        bf[nt] = *(const bf16x8*)&Bs[(wn * 32 + nt * 16 + lm) * 72 + ko];
#pragma unroll
      for (int nt = 0; nt < 2; ++nt)
#pragma unroll
        for (int mt = 0; mt < 4; ++mt)
          acc[mt][nt] = __builtin_amdgcn_mfma_f32_16x16x32_bf16(af[mt], bf[nt], acc[mt][nt], 0, 0, 0);
    }
  }

#pragma unroll
  for (int nt = 0; nt < 2; ++nt) {
    const int ncol = n0 + wn * 32 + nt * 16 + lm;
    const int mrow = m0 + wm * 64 + q * 4;
    uint16_t* dst = isH ? Hh16 : Htf;
    const float bias = isH ? pb[ncol] : 0.f;
#pragma unroll
    for (int mt = 0; mt < 4; ++mt)
#pragma unroll
      for (int r = 0; r < 4; ++r)
        dst[(size_t)(mrow + mt * 16 + r) * D3 + ncol] = f16b(acc[mt][nt][r] + bias);
  }
}

// ---------------------------------------------------------------------------
// Kernel 3: pairwise GEMM v14 (frozen) — 12 waves = (iw x jh x kh); wave does
// full 48x80 tile of its i for its K=64 half of each 128-K phase; wave pairs
// reduce acc at the end through dead Stg. 3 pair-bufs, issue-after-barrier,
// counted vmcnt 4/2, XOR-swizzle, wrap prefetch, LDS 150528 -> 1 block/CU.
// grid 256, 768 threads.
// ---------------------------------------------------------------------------
#define HT_LDS 12288                     // 96 rows x 128 B
#define CH_B 22528                       // one chunk: 22 issues x 1024
#define NISS 22
#define NKC 36                           // K chunks of 64
#define NPH 18                           // phases of 2 chunks

__global__ __launch_bounds__(768, 1) void k_pairs(const uint16_t* __restrict__ Hh,
                                                  const uint16_t* __restrict__ Htb,
                                                  const uint16_t* __restrict__ Wb,
                                                  const float* __restrict__ relb,
                                                  float* __restrict__ out) {
  const int blk = blockIdx.x;
  const int b = blk >> 5, ii = blk & 31;
  const int t = threadIdx.x;
  const int w = t >> 6, lane = t & 63;
  const int lm = lane & 15, q = lane >> 4;
  const int iw = w >> 2;            // which of the 3 i's
  const int jh = (w >> 1) & 1;      // j-half (48 rows)
  const int kh = w & 1;             // K-half of each phase
  const int i = ii * 3 + iw;

  __shared__ __align__(16) uint16_t Hr[7680];             // 15360 B
  __shared__ __align__(16) uint16_t Stg[3][CH_B];         // 3 pair-bufs x 45056 B

  // ---- one-time: stage the 3 Hh rows (linear; issue idx 13 runs 512 B past
  //      the 3 rows — covered by Hh's slack) ----
  {
    const char* hh = (const char*)(Hh + ((size_t)b * SS + ii * 3) * D3);
#pragma unroll
    for (int r = 0; r < 2; ++r) {
      const int idx = w + 12 * r;
      if (idx < 14) glld16(hh + idx * 1024 + lane * 16, (char*)Hr + idx * 1024);
    }
  }

  // ---- per-lane k0-invariant inverse-swizzled source pointers.
  //      LDS byte beta holds elem (real>>1) of its row, real = off^((row&7)<<4).
  //      Issues per wave per chunk: w0-9: 2, w10-11: 1.
  const char* rp[2];
#pragma unroll
  for (int r = 0; r < 2; ++r) {
    const int idx = w + 12 * r;
    rp[r] = nullptr;
    if (idx < NISS) {
      const int beta = idx * 1024 + lane * 16;
      if (beta < HT_LDS) {
        const int row = beta >> 7;
        const int real = (beta & 127) ^ ((row & 7) << 4);
        rp[r] = (const char*)(Htb + ((size_t)b * SS + row) * D3 + (real >> 1));
      } else {
        const int bb = beta - HT_LDS;
        const int row = bb >> 7;
        const int real = (bb & 127) ^ ((row & 7) << 4);
        rp[r] = (const char*)(Wb + (size_t)row * D3 + (real >> 1));
      }
    }
  }

  // ---- prologue: stage pairs 0 and 1 ----
#pragma unroll
  for (int pp = 0; pp < 2; ++pp)
#pragma unroll
    for (int kc = 0; kc < 2; ++kc)
#pragma unroll
      for (int r = 0; r < 2; ++r)
        if (rp[r])
          glld16(rp[r] + (size_t)128 * (2 * pp + kc),
                 (char*)Stg[pp] + kc * CH_B + (w + 12 * r) * 1024);

  f32x4 acc[3][5];
#pragma unroll
  for (int mt = 0; mt < 3; ++mt)
#pragma unroll
    for (int nt = 0; nt < 5; ++nt) acc[mt][nt] = (f32x4){0.f, 0.f, 0.f, 0.f};

  const f16x8 zro = {0, 0, 0, 0, 0, 0, 0, 0};

  for (int p = 0; p < NPH; ++p) {
    // drain pair-p loads (and Hr on phase 0); keep pair p+1 in flight.
    if (w < 10) VMW(4); else VMW(2);
    __builtin_amdgcn_s_barrier();   // all waves' pair-p loads visible
    __builtin_amdgcn_sched_barrier(0);

    // issue pair p+2 into buf[(p+2)%3] — overlaps this phase's compute.
    // Past the end it WRAPS (dead buffer, always-valid addrs, uniform vmcnt).
    {
      char* dst = (char*)Stg[(p + 2) % 3];
      int pn = p + 2;
      if (pn >= NPH) pn -= NPH;
#pragma unroll
      for (int kc = 0; kc < 2; ++kc)
#pragma unroll
        for (int r = 0; r < 2; ++r)
          if (rp[r])
            glld16(rp[r] + (size_t)128 * (2 * pn + kc),
                   dst + kc * CH_B + (w + 12 * r) * 1024);
    }

    // this wave computes only its K-half (kh) of the 128-K phase.
    const char* S = (const char*)Stg[p % 3] + kh * CH_B;
    const int k0 = (2 * p + kh) * 64;
#pragma unroll
    for (int kk = 0; kk < 2; ++kk) {
      const int ko = kk * 32 + q * 8;
      const int xb = (ko * 2) ^ ((lane & 7) << 4);  // swizzled byte off
      const f16x8 hv = *(const f16x8*)&Hr[iw * D3 + k0 + ko];
      f16x8 af[3];
#pragma unroll
      for (int mt = 0; mt < 3; ++mt) {
        const f16x8 s = *(const f16x8*)(S + (jh * 48 + mt * 16 + lm) * 128 + xb) + hv;
        af[mt] = __builtin_elementwise_max(s, zro);
      }
      f16x8 bfv[5];
#pragma unroll
      for (int nt = 0; nt < 5; ++nt)
        bfv[nt] = *(const f16x8*)(S + HT_LDS + (nt * 16 + lm) * 128 + xb);
      __builtin_amdgcn_s_setprio(1);
#pragma unroll
      for (int nt = 0; nt < 5; ++nt)
#pragma unroll
        for (int mt = 0; mt < 3; ++mt)
          acc[mt][nt] = __builtin_amdgcn_mfma_f32_16x16x32_f16(af[mt], bfv[nt], acc[mt][nt], 0, 0, 0);
      __builtin_amdgcn_s_setprio(0);
    }
    // retire all own ds_reads before arriving at the next barrier, so the
    // DMA overwrite of buf[p%3] (issued after barrier p+1) cannot race them.
    asm volatile("s_waitcnt lgkmcnt(0)" ::: "memory");
    __builtin_amdgcn_sched_barrier(0);
  }

  // ---- cross-wave kh reduction through the (now dead) Stg LDS. ----
  // __syncthreads drains this wave's DMAs (incl. wrap prefetches) and
  // barriers, so no stale glld16 can land in Stg after this point.
  __syncthreads();
  float* RED = (float*)&Stg[0][0];  // 6 pairs x 15 slots x 1024 B = 92160 B
  if (w & 1) {
#pragma unroll
    for (int mt = 0; mt < 3; ++mt)
#pragma unroll
      for (int nt = 0; nt < 5; ++nt)
        *(f32x4*)&RED[(((w >> 1) * 15 + mt * 5 + nt) << 8) + lane * 4] = acc[mt][nt];
  }
  __syncthreads();
  if (!(w & 1)) {
    // epilogue: C layout col=lm (c), row=q*4+r (j within 16-tile)
#pragma unroll
    for (int nt = 0; nt < 5; ++nt) {
      const int c = nt * 16 + lm;
      if (c < NC) {
        const float rb = relb[c];
        const int rr = c / 3, tg = c % 3;
#pragma unroll
        for (int mt = 0; mt < 3; ++mt) {
          const f32x4 oth = *(const f32x4*)&RED[(((w >> 1) * 15 + mt * 5 + nt) << 8) + lane * 4];
          const int j0 = jh * 48 + mt * 16 + q * 4;
          float* base = out + ((((size_t)b * TAG + tg) * RR + rr) * SS + i) * SS + j0;
          float4 o;
          o.x = acc[mt][nt][0] + oth[0] + rb;
          o.y = acc[mt][nt][1] + oth[1] + rb;
          o.z = acc[mt][nt][2] + oth[2] + rb;
          o.w = acc[mt][nt][3] + oth[3] + rb;
          *(float4*)base = o;
        }
      }
    }
  }
}

// ---------------------------------------------------------------------------
extern "C" void kernel_launch(void* const* d_in, const int* in_sizes, int n_in,
                              void* d_out, int out_size, void* d_ws, size_t ws_size,
                              hipStream_t stream) {
  const float* enc   = (const float*)d_in[0];  // [8,96,768]
  const float* rel   = (const float*)d_in[1];  // [24,8,768]
  const float* projW = (const float*)d_in[2];  // [1536,2304]
  const float* projb = (const float*)d_in[3];  // [2304]
  const float* relW  = (const float*)d_in[4];  // [2304,72]
  const float* relb  = (const float*)d_in[5];  // [72]
  float* out = (float*)d_out;                  // [8,3,24,96,96]

  uint16_t* Hh16 = (uint16_t*)d_ws;                       // 768*2304 f16 (+512 slack)
  uint16_t* Htf  = Hh16 + (size_t)DD * D3 + 512;          // 768*2304 f16
  uint16_t* Wb   = Htf + (size_t)DD * D3;                 // 96*2304 f16 (80 used)
  uint16_t* Tp   = Wb + (size_t)96 * D3;                  // 2304*1536 bf16
  uint16_t* Ab   = Tp + (size_t)D3 * 2 * DD;              // 768*768 bf16
  float* Pst = (float*)(Ab + (size_t)DD * DD);            // 8*8*96 f32
  float* SG = Pst + (size_t)BB * RSEQ * SS;               // 8*8*104 f32

  hipMemsetAsync(SG, 0, (size_t)BB * RSEQ * 104 * sizeof(float), stream);
  k_prep0<<<1028, 256, 0, stream>>>(relW, Wb, projW, Tp, enc, rel, SG);
  k_refS<<<BB, 64, 0, stream>>>(SG, Pst);
  k_refB<<<96, 256, 0, stream>>>(enc, rel, Pst, Ab);
  k_proj<<<dim3(6, 72), 256, 0, stream>>>(Ab, Tp, projb, Hh16, Htf);
  k_pairs<<<256, 768, 0, stream>>>(Hh16, Htf, Wb, relb, out);
}

// Round 12
// 200.669 us; speedup vs baseline: 1.0020x; 1.0013x over previous
//
#include <hip/hip_runtime.h>
#include <hip/hip_bf16.h>
#include <math.h>
#include <stdint.h>
#include <string.h>

#define BB 8
#define SS 96
#define DD 768
#define RR 24
#define RSEQ 8
#define TAG 3
#define D3 2304   // 3*D
#define NC 72     // R*TAG

typedef __attribute__((ext_vector_type(8))) short bf16x8;
typedef __attribute__((ext_vector_type(4))) float f32x4;
typedef _Float16 f16x8 __attribute__((ext_vector_type(8)));
typedef _Float16 f16x2 __attribute__((ext_vector_type(2)));

// async global->LDS, 16 B/lane; LDS dest = wave-uniform base + lane*16.
typedef __attribute__((address_space(3))) uint8_t lds_u8;
typedef const __attribute__((address_space(1))) uint8_t glb_u8;
static __device__ __forceinline__ void glld16(const void* g, void* l) {
  __builtin_amdgcn_global_load_lds((glb_u8*)g, (lds_u8*)l, 16, 0, 0);
}

#define VMW(N) asm volatile("s_waitcnt vmcnt(" #N ")" ::: "memory")

// round-half-up f32 pair -> packed bf16x2: add,add,v_perm = 3 VALU.
static __device__ inline uint32_t pkrhu(float lo, float hi) {
  uint32_t a, b;
  memcpy(&a, &lo, 4);
  memcpy(&b, &hi, 4);
  return __builtin_amdgcn_perm(b + 0x8000u, a + 0x8000u, 0x07060302u);
}
static __device__ inline uint32_t pkrne(float lo, float hi) {
  uint32_t a, b;
  memcpy(&a, &lo, 4);
  memcpy(&b, &hi, 4);
  a += 0x7FFFu + ((a >> 16) & 1u);
  b += 0x7FFFu + ((b >> 16) & 1u);
  return (a >> 16) | (b & 0xFFFF0000u);
}
// f32 pair -> packed f16x2 (v_cvt_f16_f32 x2 + pack)
static __device__ inline uint32_t pkf16(float lo, float hi) {
  union { f16x2 h; uint32_t u; } r;
  r.h[0] = (_Float16)lo;
  r.h[1] = (_Float16)hi;
  return r.u;
}
static __device__ inline uint16_t f16b(float v) {
  union { _Float16 h; uint16_t u; } r;
  r.h = (_Float16)v;
  return r.u;
}

// ---------------------------------------------------------------------------
// Kernel 0 (fused prep): blocks 0..35 = prepW (rel_W^T -> f16), 36..899 =
// proj_W transpose (bf16, feeds k_proj MFMA), 900..1027 = S0/G k-split
// partial dots (atomicAdd into pre-zeroed SG).
// ---------------------------------------------------------------------------
__global__ __launch_bounds__(256) void k_prep0(const float* __restrict__ relW,
                                               uint16_t* __restrict__ Wb,
                                               const float* __restrict__ projW,
                                               uint16_t* __restrict__ Tp,
                                               const float* __restrict__ enc,
                                               const float* __restrict__ rel,
                                               float* __restrict__ SG) {
  __shared__ __align__(16) char smem[24704];
  const int blk = blockIdx.x;
  const int t = threadIdx.x;

  if (blk < 36) {
    // ---- Wb[96][2304] f16 = rel_W^T (rows 72..79 zero; 80..95 untouched) ----
    float* tile = (float*)smem;  // 64*72 f32
    const int k0 = blk * 64;
    const float* src = relW + (size_t)k0 * NC;
    for (int e = t; e < 64 * NC / 4; e += 256) ((float4*)tile)[e] = ((const float4*)src)[e];
    __syncthreads();
    for (int u = t; u < 80 * 16; u += 256) {
      const int n = u >> 4, kq = (u & 15) * 4;
      uint2 w = {0u, 0u};
      if (n < NC) {
        w.x = pkf16(tile[(kq + 0) * NC + n], tile[(kq + 1) * NC + n]);
        w.y = pkf16(tile[(kq + 2) * NC + n], tile[(kq + 3) * NC + n]);
      }
      *(uint2*)&Wb[(size_t)n * D3 + k0 + kq] = w;
    }
  } else if (blk < 900) {
    // ---- Tp[2304][1536] bf16 = proj_W^T, 64x64 tile ----
    const int bx = blk - 36;
    float (*tile)[65] = (float(*)[65])smem;
    const int c0 = (bx % 36) * 64;
    const int r0 = (bx / 36) * 64;
    {
      const int tr = t >> 4;
      const int tc4 = (t & 15) * 4;
#pragma unroll
      for (int p = 0; p < 4; ++p) {
        const int r = tr + p * 16;
        const float4 v = *(const float4*)&projW[(size_t)(r0 + r) * D3 + c0 + tc4];
        tile[r][tc4 + 0] = v.x;
        tile[r][tc4 + 1] = v.y;
        tile[r][tc4 + 2] = v.z;
        tile[r][tc4 + 3] = v.w;
      }
    }
    __syncthreads();
    {
      const int cc = t >> 4;
      const int rr4 = (t & 15) * 4;
#pragma unroll
      for (int p = 0; p < 4; ++p) {
        const int c = cc + p * 16;
        uint2 w;
        w.x = pkrne(tile[rr4 + 0][c], tile[rr4 + 1][c]);
        w.y = pkrne(tile[rr4 + 2][c], tile[rr4 + 3][c]);
        *(uint2*)&Tp[(size_t)(c0 + c) * (2 * DD) + r0 + rr4] = w;
      }
    }
  } else {
    // ---- S0/G partial: sample b, d-chunk [d0, d0+48). ----
    const int idx = blk - 900;
    const int b = idx >> 4;
    const int d0 = (idx & 15) * 48;
    float (*AsF)[48] = (float(*)[48])smem;  // 8 x 48 f32 = 1.5 KB

    if (t < 96) {
      const int r = t / 12, q4 = (t % 12) * 4;
      *(float4*)&AsF[r][q4] = *(const float4*)&rel[((size_t)b * RSEQ + r) * DD + d0 + q4];
    }
    __syncthreads();

    for (int e = t; e < RSEQ * (SS + RSEQ); e += 256) {
      const int r = e & 7, s = e >> 3;
      const float* row = (s < SS) ? (enc + ((size_t)b * SS + s) * DD + d0) : &AsF[s - SS][0];
      float a0 = 0.f, a1 = 0.f, a2 = 0.f, a3 = 0.f;
#pragma unroll
      for (int d = 0; d < 48; d += 4) {
        const float4 rv = *(const float4*)&row[d];
        a0 += AsF[r][d + 0] * rv.x;
        a1 += AsF[r][d + 1] * rv.y;
        a2 += AsF[r][d + 2] * rv.z;
        a3 += AsF[r][d + 3] * rv.w;
      }
      atomicAdd(&SG[((size_t)b * RSEQ + r) * 104 + s], (a0 + a1) + (a2 + a3));
    }
  }
}

// ---------------------------------------------------------------------------
// Kernel 1a v5: refine serial core — v4's level-major ILP structure, with
// __launch_bounds__(64, 1): min-waves/EU=1 unlocks the full VGPR budget.
// v3/v4 compiled to 40 VGPRs (allocator targeted default occupancy), forcing
// g[8][8]+P+score arrays into SCRATCH — every FMA operand was a ~200cy
// scratch load, hence 60us at VALUBusy 0.3%. With registers unlocked the
// whole state (~160 VGPR) is register-resident and statically indexed.
// grid 8 x 64.
// ---------------------------------------------------------------------------
__global__ __launch_bounds__(64, 1) void k_refS(const float* __restrict__ SG,
                                                float* __restrict__ Pst) {
  const int b = blockIdx.x;
  const int l = threadIdx.x;
  const float scale = 0.036084391824351613f;  // 1/sqrt(768)
  const float* base = SG + (size_t)b * RSEQ * 104;

  float g[RSEQ][RSEQ];
#pragma unroll
  for (int r = 0; r < RSEQ; ++r)
#pragma unroll
    for (int r2 = 0; r2 < RSEQ; ++r2) g[r][r2] = base[r * 104 + 96 + r2];

  float s0a[RSEQ], s0b[RSEQ], P0[RSEQ], P1[RSEQ];
#pragma unroll
  for (int r = 0; r < RSEQ; ++r) {
    s0a[r] = base[r * 104 + l];
    s0b[r] = (l < 32) ? base[r * 104 + 64 + l] : 0.f;
    P0[r] = 0.f;
    P1[r] = 0.f;
  }

  for (int step = 0; step < RR; ++step) {
    float a0[RSEQ], a1[RSEQ], mx[RSEQ];
    // 1) all 8 rows' scores (independent FMA chains — ILP)
#pragma unroll
    for (int r = 0; r < RSEQ; ++r) {
      float x0 = s0a[r], x1 = s0b[r];
#pragma unroll
      for (int r2 = 0; r2 < RSEQ; ++r2) {
        x0 += g[r][r2] * P0[r2];
        x1 += g[r][r2] * P1[r2];
      }
      a0[r] = x0 * scale;
      a1[r] = x1 * scale;
      mx[r] = fmaxf(a0[r], (l < 32) ? a1[r] : -1e30f);
    }
    // 2) max trees, level-major: 8 independent bpermutes per level pipeline
#pragma unroll
    for (int o = 32; o > 0; o >>= 1) {
      float sh[RSEQ];
#pragma unroll
      for (int r = 0; r < RSEQ; ++r) sh[r] = __shfl_xor(mx[r], o, 64);
#pragma unroll
      for (int r = 0; r < RSEQ; ++r) mx[r] = fmaxf(mx[r], sh[r]);
    }
    // 3) exps
    float e0[RSEQ], e1[RSEQ], sm[RSEQ];
#pragma unroll
    for (int r = 0; r < RSEQ; ++r) {
      e0[r] = __expf(a0[r] - mx[r]);
      e1[r] = (l < 32) ? __expf(a1[r] - mx[r]) : 0.f;
      sm[r] = e0[r] + e1[r];
    }
    // 4) sum trees, level-major
#pragma unroll
    for (int o = 32; o > 0; o >>= 1) {
      float sh[RSEQ];
#pragma unroll
      for (int r = 0; r < RSEQ; ++r) sh[r] = __shfl_xor(sm[r], o, 64);
#pragma unroll
      for (int r = 0; r < RSEQ; ++r) sm[r] += sh[r];
    }
    // 5) Jacobi update (after all rows' weights computed)
#pragma unroll
    for (int r = 0; r < RSEQ; ++r) {
      const float inv = 1.f / sm[r];
      P0[r] += e0[r] * inv;
      P1[r] += e1[r] * inv;  // 0 for l >= 32
    }
  }

  float* pb = Pst + (size_t)b * RSEQ * SS;
#pragma unroll
  for (int r = 0; r < RSEQ; ++r) {
    pb[r * SS + l] = P0[r];
    if (l < 32) pb[r * SS + 64 + l] = P1[r];
  }
}

// ---------------------------------------------------------------------------
// Kernel 1b: refine epilogue: enc' bf16 = enc + P^T @ A. grid 96 (8 rows/blk).
// ---------------------------------------------------------------------------
__global__ __launch_bounds__(256) void k_refB(const float* __restrict__ enc,
                                              const float* __restrict__ rel,
                                              const float* __restrict__ Pst,
                                              uint16_t* __restrict__ encRb) {
  const int blk = blockIdx.x;
  const int b = blk / 12;
  const int s0 = (blk % 12) * 8;
  const int t = threadIdx.x;
  __shared__ float As[RSEQ][DD + 4];
  __shared__ float Pl[RSEQ][8];

  const float* Ag = rel + (size_t)b * RSEQ * DD;
  for (int e = t; e < RSEQ * DD / 4; e += 256) {
    const int r = (e * 4) / DD, d = (e * 4) % DD;
    *(float4*)&As[r][d] = *(const float4*)&Ag[e * 4];
  }
  if (t < RSEQ * 8) {
    const int r = t >> 3, sl = t & 7;
    Pl[r][sl] = Pst[(size_t)b * RSEQ * SS + r * SS + s0 + sl];
  }
  __syncthreads();

  const float* Eb = enc + ((size_t)b * SS + s0) * DD;
  uint16_t* Ob = encRb + ((size_t)b * SS + s0) * DD;
  for (int e = t; e < 8 * DD / 4; e += 256) {
    const int sl = (e * 4) / DD, d = (e * 4) % DD;
    float4 v = ((const float4*)Eb)[e];
#pragma unroll
    for (int r = 0; r < RSEQ; ++r) {
      const float p = Pl[r][sl];
      v.x += p * As[r][d + 0];
      v.y += p * As[r][d + 1];
      v.z += p * As[r][d + 2];
      v.w += p * As[r][d + 3];
    }
    uint2 w;
    w.x = pkrhu(v.x, v.y);
    w.y = pkrhu(v.z, v.w);
    *(uint2*)&Ob[e * 4] = w;
  }
}

// ---------------------------------------------------------------------------
// Kernel 2 v2: projection GEMM — 128x64 tiles: reads/MFMA 0.75, 432 blocks.
// glld16 2-barrier schedule. LDS 27648 B -> 4 blocks/CU. grid (6,72).
// ---------------------------------------------------------------------------
__global__ __launch_bounds__(256, 4) void k_proj(const uint16_t* __restrict__ Ab,
                                                 const uint16_t* __restrict__ Bt,
                                                 const float* __restrict__ pb,
                                                 uint16_t* __restrict__ Hh16,
                                                 uint16_t* __restrict__ Htf) {
  const int m0 = blockIdx.x * 128;
  const int gn0 = blockIdx.y * 64;
  const bool isH = gn0 < D3;               // uniform per block
  const int n0 = isH ? gn0 : gn0 - D3;
  const int halfk = isH ? 0 : DD;
  const int t = threadIdx.x, w = t >> 6, lane = t & 63;
  const int wm = w >> 1, wn = w & 1;
  const int lm = lane & 15, q = lane >> 4;

  __shared__ __align__(16) uint16_t As[128 * 72];  // 18432 B (18 issues)
  __shared__ __align__(16) uint16_t Bs[64 * 72];   //  9216 B (9 issues)

  const char* rp[7];
  char* lp[7];
#pragma unroll
  for (int r = 0; r < 7; ++r) {
    const int idx = w + 4 * r;
    rp[r] = nullptr;
    lp[r] = nullptr;
    if (idx < 27) {
      const int ii = (idx < 18) ? idx : idx - 18;
      const int beta = ii * 1024 + lane * 16;
      const int elem = beta >> 1;
      const int row = elem / 72;
      int o = elem - row * 72;
      if (o >= 64) o = 0;  // pad lanes: safe addr, land in LDS row pad
      if (idx < 18) {
        rp[r] = (const char*)(Ab + (size_t)(m0 + row) * DD + o);
        lp[r] = (char*)As + ii * 1024;
      } else {
        rp[r] = (const char*)(Bt + (size_t)(n0 + row) * (2 * DD) + halfk + o);
        lp[r] = (char*)Bs + ii * 1024;
      }
    }
  }

  f32x4 acc[4][2];
#pragma unroll
  for (int a = 0; a < 4; ++a)
#pragma unroll
    for (int c = 0; c < 2; ++c) acc[a][c] = (f32x4){0.f, 0.f, 0.f, 0.f};

  for (int k0 = 0; k0 < DD; k0 += 64) {
    __syncthreads();
#pragma unroll
    for (int r = 0; r < 7; ++r)
      if (rp[r]) glld16(rp[r] + 2 * k0, lp[r]);
    __syncthreads();
#pragma unroll
    for (int kk = 0; kk < 2; ++kk) {
      const int ko = kk * 32 + q * 8;
      bf16x8 af[4], bf[2];
#pragma unroll
      for (int mt = 0; mt < 4; ++mt)
        af[mt] = *(const bf16x8*)&As[(wm * 64 + mt * 16 + lm) * 72 + ko];
#pragma unroll
      for (int nt = 0; nt < 2; ++nt)
        bf[nt] = *(const bf16x8*)&Bs[(wn * 32 + nt * 16 + lm) * 72 + ko];
#pragma unroll
      for (int nt = 0; nt < 2; ++nt)
#pragma unroll
        for (int mt = 0; mt < 4; ++mt)
          acc[mt][nt] = __builtin_amdgcn_mfma_f32_16x16x32_bf16(af[mt], bf[nt], acc[mt][nt], 0, 0, 0);
    }
  }

#pragma unroll
  for (int nt = 0; nt < 2; ++nt) {
    const int ncol = n0 + wn * 32 + nt * 16 + lm;
    const int mrow = m0 + wm * 64 + q * 4;
    uint16_t* dst = isH ? Hh16 : Htf;
    const float bias = isH ? pb[ncol] : 0.f;
#pragma unroll
    for (int mt = 0; mt < 4; ++mt)
#pragma unroll
      for (int r = 0; r < 4; ++r)
        dst[(size_t)(mrow + mt * 16 + r) * D3 + ncol] = f16b(acc[mt][nt][r] + bias);
  }
}

// ---------------------------------------------------------------------------
// Kernel 3: pairwise GEMM v14 (frozen) — 12 waves = (iw x jh x kh); wave does
// full 48x80 tile of its i for its K=64 half of each 128-K phase; wave pairs
// reduce acc at the end through dead Stg. 3 pair-bufs, issue-after-barrier,
// counted vmcnt 4/2, XOR-swizzle, wrap prefetch, LDS 150528 -> 1 block/CU.
// grid 256, 768 threads.
// ---------------------------------------------------------------------------
#define HT_LDS 12288                     // 96 rows x 128 B
#define CH_B 22528                       // one chunk: 22 issues x 1024
#define NISS 22
#define NKC 36                           // K chunks of 64
#define NPH 18                           // phases of 2 chunks

__global__ __launch_bounds__(768, 1) void k_pairs(const uint16_t* __restrict__ Hh,
                                                  const uint16_t* __restrict__ Htb,
                                                  const uint16_t* __restrict__ Wb,
                                                  const float* __restrict__ relb,
                                                  float* __restrict__ out) {
  const int blk = blockIdx.x;
  const int b = blk >> 5, ii = blk & 31;
  const int t = threadIdx.x;
  const int w = t >> 6, lane = t & 63;
  const int lm = lane & 15, q = lane >> 4;
  const int iw = w >> 2;            // which of the 3 i's
  const int jh = (w >> 1) & 1;      // j-half (48 rows)
  const int kh = w & 1;             // K-half of each phase
  const int i = ii * 3 + iw;

  __shared__ __align__(16) uint16_t Hr[7680];             // 15360 B
  __shared__ __align__(16) uint16_t Stg[3][CH_B];         // 3 pair-bufs x 45056 B

  // ---- one-time: stage the 3 Hh rows (linear; issue idx 13 runs 512 B past
  //      the 3 rows — covered by Hh's slack) ----
  {
    const char* hh = (const char*)(Hh + ((size_t)b * SS + ii * 3) * D3);
#pragma unroll
    for (int r = 0; r < 2; ++r) {
      const int idx = w + 12 * r;
      if (idx < 14) glld16(hh + idx * 1024 + lane * 16, (char*)Hr + idx * 1024);
    }
  }

  // ---- per-lane k0-invariant inverse-swizzled source pointers.
  //      LDS byte beta holds elem (real>>1) of its row, real = off^((row&7)<<4).
  //      Issues per wave per chunk: w0-9: 2, w10-11: 1.
  const char* rp[2];
#pragma unroll
  for (int r = 0; r < 2; ++r) {
    const int idx = w + 12 * r;
    rp[r] = nullptr;
    if (idx < NISS) {
      const int beta = idx * 1024 + lane * 16;
      if (beta < HT_LDS) {
        const int row = beta >> 7;
        const int real = (beta & 127) ^ ((row & 7) << 4);
        rp[r] = (const char*)(Htb + ((size_t)b * SS + row) * D3 + (real >> 1));
      } else {
        const int bb = beta - HT_LDS;
        const int row = bb >> 7;
        const int real = (bb & 127) ^ ((row & 7) << 4);
        rp[r] = (const char*)(Wb + (size_t)row * D3 + (real >> 1));
      }
    }
  }

  // ---- prologue: stage pairs 0 and 1 ----
#pragma unroll
  for (int pp = 0; pp < 2; ++pp)
#pragma unroll
    for (int kc = 0; kc < 2; ++kc)
#pragma unroll
      for (int r = 0; r < 2; ++r)
        if (rp[r])
          glld16(rp[r] + (size_t)128 * (2 * pp + kc),
                 (char*)Stg[pp] + kc * CH_B + (w + 12 * r) * 1024);

  f32x4 acc[3][5];
#pragma unroll
  for (int mt = 0; mt < 3; ++mt)
#pragma unroll
    for (int nt = 0; nt < 5; ++nt) acc[mt][nt] = (f32x4){0.f, 0.f, 0.f, 0.f};

  const f16x8 zro = {0, 0, 0, 0, 0, 0, 0, 0};

  for (int p = 0; p < NPH; ++p) {
    // drain pair-p loads (and Hr on phase 0); keep pair p+1 in flight.
    if (w < 10) VMW(4); else VMW(2);
    __builtin_amdgcn_s_barrier();   // all waves' pair-p loads visible
    __builtin_amdgcn_sched_barrier(0);

    // issue pair p+2 into buf[(p+2)%3] — overlaps this phase's compute.
    // Past the end it WRAPS (dead buffer, always-valid addrs, uniform vmcnt).
    {
      char* dst = (char*)Stg[(p + 2) % 3];
      int pn = p + 2;
      if (pn >= NPH) pn -= NPH;
#pragma unroll
      for (int kc = 0; kc < 2; ++kc)
#pragma unroll
        for (int r = 0; r < 2; ++r)
          if (rp[r])
            glld16(rp[r] + (size_t)128 * (2 * pn + kc),
                   dst + kc * CH_B + (w + 12 * r) * 1024);
    }

    // this wave computes only its K-half (kh) of the 128-K phase.
    const char* S = (const char*)Stg[p % 3] + kh * CH_B;
    const int k0 = (2 * p + kh) * 64;
#pragma unroll
    for (int kk = 0; kk < 2; ++kk) {
      const int ko = kk * 32 + q * 8;
      const int xb = (ko * 2) ^ ((lane & 7) << 4);  // swizzled byte off
      const f16x8 hv = *(const f16x8*)&Hr[iw * D3 + k0 + ko];
      f16x8 af[3];
#pragma unroll
      for (int mt = 0; mt < 3; ++mt) {
        const f16x8 s = *(const f16x8*)(S + (jh * 48 + mt * 16 + lm) * 128 + xb) + hv;
        af[mt] = __builtin_elementwise_max(s, zro);
      }
      f16x8 bfv[5];
#pragma unroll
      for (int nt = 0; nt < 5; ++nt)
        bfv[nt] = *(const f16x8*)(S + HT_LDS + (nt * 16 + lm) * 128 + xb);
      __builtin_amdgcn_s_setprio(1);
#pragma unroll
      for (int nt = 0; nt < 5; ++nt)
#pragma unroll
        for (int mt = 0; mt < 3; ++mt)
          acc[mt][nt] = __builtin_amdgcn_mfma_f32_16x16x32_f16(af[mt], bfv[nt], acc[mt][nt], 0, 0, 0);
      __builtin_amdgcn_s_setprio(0);
    }
    // retire all own ds_reads before arriving at the next barrier, so the
    // DMA overwrite of buf[p%3] (issued after barrier p+1) cannot race them.
    asm volatile("s_waitcnt lgkmcnt(0)" ::: "memory");
    __builtin_amdgcn_sched_barrier(0);
  }

  // ---- cross-wave kh reduction through the (now dead) Stg LDS. ----
  // __syncthreads drains this wave's DMAs (incl. wrap prefetches) and
  // barriers, so no stale glld16 can land in Stg after this point.
  __syncthreads();
  float* RED = (float*)&Stg[0][0];  // 6 pairs x 15 slots x 1024 B = 92160 B
  if (w & 1) {
#pragma unroll
    for (int mt = 0; mt < 3; ++mt)
#pragma unroll
      for (int nt = 0; nt < 5; ++nt)
        *(f32x4*)&RED[(((w >> 1) * 15 + mt * 5 + nt) << 8) + lane * 4] = acc[mt][nt];
  }
  __syncthreads();
  if (!(w & 1)) {
    // epilogue: C layout col=lm (c), row=q*4+r (j within 16-tile)
#pragma unroll
    for (int nt = 0; nt < 5; ++nt) {
      const int c = nt * 16 + lm;
      if (c < NC) {
        const float rb = relb[c];
        const int rr = c / 3, tg = c % 3;
#pragma unroll
        for (int mt = 0; mt < 3; ++mt) {
          const f32x4 oth = *(const f32x4*)&RED[(((w >> 1) * 15 + mt * 5 + nt) << 8) + lane * 4];
          const int j0 = jh * 48 + mt * 16 + q * 4;
          float* base = out + ((((size_t)b * TAG + tg) * RR + rr) * SS + i) * SS + j0;
          float4 o;
          o.x = acc[mt][nt][0] + oth[0] + rb;
          o.y = acc[mt][nt][1] + oth[1] + rb;
          o.z = acc[mt][nt][2] + oth[2] + rb;
          o.w = acc[mt][nt][3] + oth[3] + rb;
          *(float4*)base = o;
        }
      }
    }
  }
}

// ---------------------------------------------------------------------------
extern "C" void kernel_launch(void* const* d_in, const int* in_sizes, int n_in,
                              void* d_out, int out_size, void* d_ws, size_t ws_size,
                              hipStream_t stream) {
  const float* enc   = (const float*)d_in[0];  // [8,96,768]
  const float* rel   = (const float*)d_in[1];  // [24,8,768]
  const float* projW = (const float*)d_in[2];  // [1536,2304]
  const float* projb = (const float*)d_in[3];  // [2304]
  const float* relW  = (const float*)d_in[4];  // [2304,72]
  const float* relb  = (const float*)d_in[5];  // [72]
  float* out = (float*)d_out;                  // [8,3,24,96,96]

  uint16_t* Hh16 = (uint16_t*)d_ws;                       // 768*2304 f16 (+512 slack)
  uint16_t* Htf  = Hh16 + (size_t)DD * D3 + 512;          // 768*2304 f16
  uint16_t* Wb   = Htf + (size_t)DD * D3;                 // 96*2304 f16 (80 used)
  uint16_t* Tp   = Wb + (size_t)96 * D3;                  // 2304*1536 bf16
  uint16_t* Ab   = Tp + (size_t)D3 * 2 * DD;              // 768*768 bf16
  float* Pst = (float*)(Ab + (size_t)DD * DD);            // 8*8*96 f32
  float* SG = Pst + (size_t)BB * RSEQ * SS;               // 8*8*104 f32

  hipMemsetAsync(SG, 0, (size_t)BB * RSEQ * 104 * sizeof(float), stream);
  k_prep0<<<1028, 256, 0, stream>>>(relW, Wb, projW, Tp, enc, rel, SG);
  k_refS<<<BB, 64, 0, stream>>>(SG, Pst);
  k_refB<<<96, 256, 0, stream>>>(enc, rel, Pst, Ab);
  k_proj<<<dim3(6, 72), 256, 0, stream>>>(Ab, Tp, projb, Hh16, Htf);
  k_pairs<<<256, 768, 0, stream>>>(Hh16, Htf, Wb, relb, out);
}

// Round 13
// 187.086 us; speedup vs baseline: 1.0747x; 1.0726x over previous
//
#include <hip/hip_runtime.h>
#include <hip/hip_bf16.h>
#include <math.h>
#include <stdint.h>
#include <string.h>

#define BB 8
#define SS 96
#define DD 768
#define RR 24
#define RSEQ 8
#define TAG 3
#define D3 2304   // 3*D
#define NC 72     // R*TAG

typedef __attribute__((ext_vector_type(8))) short bf16x8;
typedef __attribute__((ext_vector_type(4))) float f32x4;
typedef _Float16 f16x8 __attribute__((ext_vector_type(8)));
typedef _Float16 f16x2 __attribute__((ext_vector_type(2)));

// async global->LDS, 16 B/lane; LDS dest = wave-uniform base + lane*16.
typedef __attribute__((address_space(3))) uint8_t lds_u8;
typedef const __attribute__((address_space(1))) uint8_t glb_u8;
static __device__ __forceinline__ void glld16(const void* g, void* l) {
  __builtin_amdgcn_global_load_lds((glb_u8*)g, (lds_u8*)l, 16, 0, 0);
}

#define VMW(N) asm volatile("s_waitcnt vmcnt(" #N ")" ::: "memory")
// pin a float to a VGPR: breaks compiler rematerialization (re-load from
// global) by making the value opaque. No code emitted.
#define PIN(x) asm volatile("" : "+v"(x))

// round-half-up f32 pair -> packed bf16x2: add,add,v_perm = 3 VALU.
static __device__ inline uint32_t pkrhu(float lo, float hi) {
  uint32_t a, b;
  memcpy(&a, &lo, 4);
  memcpy(&b, &hi, 4);
  return __builtin_amdgcn_perm(b + 0x8000u, a + 0x8000u, 0x07060302u);
}
static __device__ inline uint32_t pkrne(float lo, float hi) {
  uint32_t a, b;
  memcpy(&a, &lo, 4);
  memcpy(&b, &hi, 4);
  a += 0x7FFFu + ((a >> 16) & 1u);
  b += 0x7FFFu + ((b >> 16) & 1u);
  return (a >> 16) | (b & 0xFFFF0000u);
}
// f32 pair -> packed f16x2 (v_cvt_f16_f32 x2 + pack)
static __device__ inline uint32_t pkf16(float lo, float hi) {
  union { f16x2 h; uint32_t u; } r;
  r.h[0] = (_Float16)lo;
  r.h[1] = (_Float16)hi;
  return r.u;
}
static __device__ inline uint16_t f16b(float v) {
  union { _Float16 h; uint16_t u; } r;
  r.h = (_Float16)v;
  return r.u;
}

// ---------------------------------------------------------------------------
// Kernel 0 (fused prep): blocks 0..35 = prepW (rel_W^T -> f16), 36..899 =
// proj_W transpose (bf16, feeds k_proj MFMA), 900..1027 = S0/G k-split
// partial dots (atomicAdd into pre-zeroed SG).
// ---------------------------------------------------------------------------
__global__ __launch_bounds__(256) void k_prep0(const float* __restrict__ relW,
                                               uint16_t* __restrict__ Wb,
                                               const float* __restrict__ projW,
                                               uint16_t* __restrict__ Tp,
                                               const float* __restrict__ enc,
                                               const float* __restrict__ rel,
                                               float* __restrict__ SG) {
  __shared__ __align__(16) char smem[24704];
  const int blk = blockIdx.x;
  const int t = threadIdx.x;

  if (blk < 36) {
    // ---- Wb[96][2304] f16 = rel_W^T (rows 72..79 zero; 80..95 untouched) ----
    float* tile = (float*)smem;  // 64*72 f32
    const int k0 = blk * 64;
    const float* src = relW + (size_t)k0 * NC;
    for (int e = t; e < 64 * NC / 4; e += 256) ((float4*)tile)[e] = ((const float4*)src)[e];
    __syncthreads();
    for (int u = t; u < 80 * 16; u += 256) {
      const int n = u >> 4, kq = (u & 15) * 4;
      uint2 w = {0u, 0u};
      if (n < NC) {
        w.x = pkf16(tile[(kq + 0) * NC + n], tile[(kq + 1) * NC + n]);
        w.y = pkf16(tile[(kq + 2) * NC + n], tile[(kq + 3) * NC + n]);
      }
      *(uint2*)&Wb[(size_t)n * D3 + k0 + kq] = w;
    }
  } else if (blk < 900) {
    // ---- Tp[2304][1536] bf16 = proj_W^T, 64x64 tile ----
    const int bx = blk - 36;
    float (*tile)[65] = (float(*)[65])smem;
    const int c0 = (bx % 36) * 64;
    const int r0 = (bx / 36) * 64;
    {
      const int tr = t >> 4;
      const int tc4 = (t & 15) * 4;
#pragma unroll
      for (int p = 0; p < 4; ++p) {
        const int r = tr + p * 16;
        const float4 v = *(const float4*)&projW[(size_t)(r0 + r) * D3 + c0 + tc4];
        tile[r][tc4 + 0] = v.x;
        tile[r][tc4 + 1] = v.y;
        tile[r][tc4 + 2] = v.z;
        tile[r][tc4 + 3] = v.w;
      }
    }
    __syncthreads();
    {
      const int cc = t >> 4;
      const int rr4 = (t & 15) * 4;
#pragma unroll
      for (int p = 0; p < 4; ++p) {
        const int c = cc + p * 16;
        uint2 w;
        w.x = pkrne(tile[rr4 + 0][c], tile[rr4 + 1][c]);
        w.y = pkrne(tile[rr4 + 2][c], tile[rr4 + 3][c]);
        *(uint2*)&Tp[(size_t)(c0 + c) * (2 * DD) + r0 + rr4] = w;
      }
    }
  } else {
    // ---- S0/G partial: sample b, d-chunk [d0, d0+48). ----
    const int idx = blk - 900;
    const int b = idx >> 4;
    const int d0 = (idx & 15) * 48;
    float (*AsF)[48] = (float(*)[48])smem;  // 8 x 48 f32 = 1.5 KB

    if (t < 96) {
      const int r = t / 12, q4 = (t % 12) * 4;
      *(float4*)&AsF[r][q4] = *(const float4*)&rel[((size_t)b * RSEQ + r) * DD + d0 + q4];
    }
    __syncthreads();

    for (int e = t; e < RSEQ * (SS + RSEQ); e += 256) {
      const int r = e & 7, s = e >> 3;
      const float* row = (s < SS) ? (enc + ((size_t)b * SS + s) * DD + d0) : &AsF[s - SS][0];
      float a0 = 0.f, a1 = 0.f, a2 = 0.f, a3 = 0.f;
#pragma unroll
      for (int d = 0; d < 48; d += 4) {
        const float4 rv = *(const float4*)&row[d];
        a0 += AsF[r][d + 0] * rv.x;
        a1 += AsF[r][d + 1] * rv.y;
        a2 += AsF[r][d + 2] * rv.z;
        a3 += AsF[r][d + 3] * rv.w;
      }
      atomicAdd(&SG[((size_t)b * RSEQ + r) * 104 + s], (a0 + a1) + (a2 + a3));
    }
  }
}

// ---------------------------------------------------------------------------
// Kernel 1a v6: refine serial core — v4/v5 level-major ILP structure, with
// g/s0 PINNED to VGPRs via no-op asm. v3-v5 all compiled to VGPR=40: the
// allocator REMATERIALIZED the const-restrict loads (re-loading g from
// global per use, ~200cy L2 latency on the score chain -> 60us at VALUBusy
// 0.3%). PIN makes the loaded values opaque so they stay register-resident
// (~150 VGPR, fine at 1 wave/SIMD via launch_bounds(64,1)). grid 8 x 64.
// ---------------------------------------------------------------------------
__global__ __launch_bounds__(64, 1) void k_refS(const float* __restrict__ SG,
                                                float* __restrict__ Pst) {
  const int b = blockIdx.x;
  const int l = threadIdx.x;
  const float scale = 0.036084391824351613f;  // 1/sqrt(768)
  const float* base = SG + (size_t)b * RSEQ * 104;

  float g[RSEQ][RSEQ];
#pragma unroll
  for (int r = 0; r < RSEQ; ++r)
#pragma unroll
    for (int r2 = 0; r2 < RSEQ; ++r2) {
      g[r][r2] = base[r * 104 + 96 + r2];
      PIN(g[r][r2]);
    }

  float s0a[RSEQ], s0b[RSEQ], P0[RSEQ], P1[RSEQ];
#pragma unroll
  for (int r = 0; r < RSEQ; ++r) {
    s0a[r] = base[r * 104 + l];
    s0b[r] = (l < 32) ? base[r * 104 + 64 + l] : 0.f;
    PIN(s0a[r]);
    PIN(s0b[r]);
    P0[r] = 0.f;
    P1[r] = 0.f;
  }

  for (int step = 0; step < RR; ++step) {
    float a0[RSEQ], a1[RSEQ], mx[RSEQ];
    // 1) all 8 rows' scores (independent FMA chains — ILP)
#pragma unroll
    for (int r = 0; r < RSEQ; ++r) {
      float x0 = s0a[r], x1 = s0b[r];
#pragma unroll
      for (int r2 = 0; r2 < RSEQ; ++r2) {
        x0 += g[r][r2] * P0[r2];
        x1 += g[r][r2] * P1[r2];
      }
      a0[r] = x0 * scale;
      a1[r] = x1 * scale;
      mx[r] = fmaxf(a0[r], (l < 32) ? a1[r] : -1e30f);
    }
    // 2) max trees, level-major: 8 independent bpermutes per level pipeline
#pragma unroll
    for (int o = 32; o > 0; o >>= 1) {
      float sh[RSEQ];
#pragma unroll
      for (int r = 0; r < RSEQ; ++r) sh[r] = __shfl_xor(mx[r], o, 64);
#pragma unroll
      for (int r = 0; r < RSEQ; ++r) mx[r] = fmaxf(mx[r], sh[r]);
    }
    // 3) exps
    float e0[RSEQ], e1[RSEQ], sm[RSEQ];
#pragma unroll
    for (int r = 0; r < RSEQ; ++r) {
      e0[r] = __expf(a0[r] - mx[r]);
      e1[r] = (l < 32) ? __expf(a1[r] - mx[r]) : 0.f;
      sm[r] = e0[r] + e1[r];
    }
    // 4) sum trees, level-major
#pragma unroll
    for (int o = 32; o > 0; o >>= 1) {
      float sh[RSEQ];
#pragma unroll
      for (int r = 0; r < RSEQ; ++r) sh[r] = __shfl_xor(sm[r], o, 64);
#pragma unroll
      for (int r = 0; r < RSEQ; ++r) sm[r] += sh[r];
    }
    // 5) Jacobi update (after all rows' weights computed)
#pragma unroll
    for (int r = 0; r < RSEQ; ++r) {
      const float inv = 1.f / sm[r];
      P0[r] += e0[r] * inv;
      P1[r] += e1[r] * inv;  // 0 for l >= 32
    }
  }

  float* pb = Pst + (size_t)b * RSEQ * SS;
#pragma unroll
  for (int r = 0; r < RSEQ; ++r) {
    pb[r * SS + l] = P0[r];
    if (l < 32) pb[r * SS + 64 + l] = P1[r];
  }
}

// ---------------------------------------------------------------------------
// Kernel 1b: refine epilogue: enc' bf16 = enc + P^T @ A. grid 96 (8 rows/blk).
// ---------------------------------------------------------------------------
__global__ __launch_bounds__(256) void k_refB(const float* __restrict__ enc,
                                              const float* __restrict__ rel,
                                              const float* __restrict__ Pst,
                                              uint16_t* __restrict__ encRb) {
  const int blk = blockIdx.x;
  const int b = blk / 12;
  const int s0 = (blk % 12) * 8;
  const int t = threadIdx.x;
  __shared__ float As[RSEQ][DD + 4];
  __shared__ float Pl[RSEQ][8];

  const float* Ag = rel + (size_t)b * RSEQ * DD;
  for (int e = t; e < RSEQ * DD / 4; e += 256) {
    const int r = (e * 4) / DD, d = (e * 4) % DD;
    *(float4*)&As[r][d] = *(const float4*)&Ag[e * 4];
  }
  if (t < RSEQ * 8) {
    const int r = t >> 3, sl = t & 7;
    Pl[r][sl] = Pst[(size_t)b * RSEQ * SS + r * SS + s0 + sl];
  }
  __syncthreads();

  const float* Eb = enc + ((size_t)b * SS + s0) * DD;
  uint16_t* Ob = encRb + ((size_t)b * SS + s0) * DD;
  for (int e = t; e < 8 * DD / 4; e += 256) {
    const int sl = (e * 4) / DD, d = (e * 4) % DD;
    float4 v = ((const float4*)Eb)[e];
#pragma unroll
    for (int r = 0; r < RSEQ; ++r) {
      const float p = Pl[r][sl];
      v.x += p * As[r][d + 0];
      v.y += p * As[r][d + 1];
      v.z += p * As[r][d + 2];
      v.w += p * As[r][d + 3];
    }
    uint2 w;
    w.x = pkrhu(v.x, v.y);
    w.y = pkrhu(v.z, v.w);
    *(uint2*)&Ob[e * 4] = w;
  }
}

// ---------------------------------------------------------------------------
// Kernel 2 v2: projection GEMM — 128x64 tiles: reads/MFMA 0.75, 432 blocks.
// glld16 2-barrier schedule. LDS 27648 B -> 4 blocks/CU. grid (6,72).
// ---------------------------------------------------------------------------
__global__ __launch_bounds__(256, 4) void k_proj(const uint16_t* __restrict__ Ab,
                                                 const uint16_t* __restrict__ Bt,
                                                 const float* __restrict__ pb,
                                                 uint16_t* __restrict__ Hh16,
                                                 uint16_t* __restrict__ Htf) {
  const int m0 = blockIdx.x * 128;
  const int gn0 = blockIdx.y * 64;
  const bool isH = gn0 < D3;               // uniform per block
  const int n0 = isH ? gn0 : gn0 - D3;
  const int halfk = isH ? 0 : DD;
  const int t = threadIdx.x, w = t >> 6, lane = t & 63;
  const int wm = w >> 1, wn = w & 1;
  const int lm = lane & 15, q = lane >> 4;

  __shared__ __align__(16) uint16_t As[128 * 72];  // 18432 B (18 issues)
  __shared__ __align__(16) uint16_t Bs[64 * 72];   //  9216 B (9 issues)

  const char* rp[7];
  char* lp[7];
#pragma unroll
  for (int r = 0; r < 7; ++r) {
    const int idx = w + 4 * r;
    rp[r] = nullptr;
    lp[r] = nullptr;
    if (idx < 27) {
      const int ii = (idx < 18) ? idx : idx - 18;
      const int beta = ii * 1024 + lane * 16;
      const int elem = beta >> 1;
      const int row = elem / 72;
      int o = elem - row * 72;
      if (o >= 64) o = 0;  // pad lanes: safe addr, land in LDS row pad
      if (idx < 18) {
        rp[r] = (const char*)(Ab + (size_t)(m0 + row) * DD + o);
        lp[r] = (char*)As + ii * 1024;
      } else {
        rp[r] = (const char*)(Bt + (size_t)(n0 + row) * (2 * DD) + halfk + o);
        lp[r] = (char*)Bs + ii * 1024;
      }
    }
  }

  f32x4 acc[4][2];
#pragma unroll
  for (int a = 0; a < 4; ++a)
#pragma unroll
    for (int c = 0; c < 2; ++c) acc[a][c] = (f32x4){0.f, 0.f, 0.f, 0.f};

  for (int k0 = 0; k0 < DD; k0 += 64) {
    __syncthreads();
#pragma unroll
    for (int r = 0; r < 7; ++r)
      if (rp[r]) glld16(rp[r] + 2 * k0, lp[r]);
    __syncthreads();
#pragma unroll
    for (int kk = 0; kk < 2; ++kk) {
      const int ko = kk * 32 + q * 8;
      bf16x8 af[4], bf[2];
#pragma unroll
      for (int mt = 0; mt < 4; ++mt)
        af[mt] = *(const bf16x8*)&As[(wm * 64 + mt * 16 + lm) * 72 + ko];
#pragma unroll
      for (int nt = 0; nt < 2; ++nt)
        bf[nt] = *(const bf16x8*)&Bs[(wn * 32 + nt * 16 + lm) * 72 + ko];
#pragma unroll
      for (int nt = 0; nt < 2; ++nt)
#pragma unroll
        for (int mt = 0; mt < 4; ++mt)
          acc[mt][nt] = __builtin_amdgcn_mfma_f32_16x16x32_bf16(af[mt], bf[nt], acc[mt][nt], 0, 0, 0);
    }
  }

#pragma unroll
  for (int nt = 0; nt < 2; ++nt) {
    const int ncol = n0 + wn * 32 + nt * 16 + lm;
    const int mrow = m0 + wm * 64 + q * 4;
    uint16_t* dst = isH ? Hh16 : Htf;
    const float bias = isH ? pb[ncol] : 0.f;
#pragma unroll
    for (int mt = 0; mt < 4; ++mt)
#pragma unroll
      for (int r = 0; r < 4; ++r)
        dst[(size_t)(mrow + mt * 16 + r) * D3 + ncol] = f16b(acc[mt][nt][r] + bias);
  }
}

// ---------------------------------------------------------------------------
// Kernel 3: pairwise GEMM v14 (frozen) — 12 waves = (iw x jh x kh); wave does
// full 48x80 tile of its i for its K=64 half of each 128-K phase; wave pairs
// reduce acc at the end through dead Stg. 3 pair-bufs, issue-after-barrier,
// counted vmcnt 4/2, XOR-swizzle, wrap prefetch, LDS 150528 -> 1 block/CU.
// grid 256, 768 threads.
// ---------------------------------------------------------------------------
#define HT_LDS 12288                     // 96 rows x 128 B
#define CH_B 22528                       // one chunk: 22 issues x 1024
#define NISS 22
#define NKC 36                           // K chunks of 64
#define NPH 18                           // phases of 2 chunks

__global__ __launch_bounds__(768, 1) void k_pairs(const uint16_t* __restrict__ Hh,
                                                  const uint16_t* __restrict__ Htb,
                                                  const uint16_t* __restrict__ Wb,
                                                  const float* __restrict__ relb,
                                                  float* __restrict__ out) {
  const int blk = blockIdx.x;
  const int b = blk >> 5, ii = blk & 31;
  const int t = threadIdx.x;
  const int w = t >> 6, lane = t & 63;
  const int lm = lane & 15, q = lane >> 4;
  const int iw = w >> 2;            // which of the 3 i's
  const int jh = (w >> 1) & 1;      // j-half (48 rows)
  const int kh = w & 1;             // K-half of each phase
  const int i = ii * 3 + iw;

  __shared__ __align__(16) uint16_t Hr[7680];             // 15360 B
  __shared__ __align__(16) uint16_t Stg[3][CH_B];         // 3 pair-bufs x 45056 B

  // ---- one-time: stage the 3 Hh rows (linear; issue idx 13 runs 512 B past
  //      the 3 rows — covered by Hh's slack) ----
  {
    const char* hh = (const char*)(Hh + ((size_t)b * SS + ii * 3) * D3);
#pragma unroll
    for (int r = 0; r < 2; ++r) {
      const int idx = w + 12 * r;
      if (idx < 14) glld16(hh + idx * 1024 + lane * 16, (char*)Hr + idx * 1024);
    }
  }

  // ---- per-lane k0-invariant inverse-swizzled source pointers.
  //      LDS byte beta holds elem (real>>1) of its row, real = off^((row&7)<<4).
  //      Issues per wave per chunk: w0-9: 2, w10-11: 1.
  const char* rp[2];
#pragma unroll
  for (int r = 0; r < 2; ++r) {
    const int idx = w + 12 * r;
    rp[r] = nullptr;
    if (idx < NISS) {
      const int beta = idx * 1024 + lane * 16;
      if (beta < HT_LDS) {
        const int row = beta >> 7;
        const int real = (beta & 127) ^ ((row & 7) << 4);
        rp[r] = (const char*)(Htb + ((size_t)b * SS + row) * D3 + (real >> 1));
      } else {
        const int bb = beta - HT_LDS;
        const int row = bb >> 7;
        const int real = (bb & 127) ^ ((row & 7) << 4);
        rp[r] = (const char*)(Wb + (size_t)row * D3 + (real >> 1));
      }
    }
  }

  // ---- prologue: stage pairs 0 and 1 ----
#pragma unroll
  for (int pp = 0; pp < 2; ++pp)
#pragma unroll
    for (int kc = 0; kc < 2; ++kc)
#pragma unroll
      for (int r = 0; r < 2; ++r)
        if (rp[r])
          glld16(rp[r] + (size_t)128 * (2 * pp + kc),
                 (char*)Stg[pp] + kc * CH_B + (w + 12 * r) * 1024);

  f32x4 acc[3][5];
#pragma unroll
  for (int mt = 0; mt < 3; ++mt)
#pragma unroll
    for (int nt = 0; nt < 5; ++nt) acc[mt][nt] = (f32x4){0.f, 0.f, 0.f, 0.f};

  const f16x8 zro = {0, 0, 0, 0, 0, 0, 0, 0};

  for (int p = 0; p < NPH; ++p) {
    // drain pair-p loads (and Hr on phase 0); keep pair p+1 in flight.
    if (w < 10) VMW(4); else VMW(2);
    __builtin_amdgcn_s_barrier();   // all waves' pair-p loads visible
    __builtin_amdgcn_sched_barrier(0);

    // issue pair p+2 into buf[(p+2)%3] — overlaps this phase's compute.
    // Past the end it WRAPS (dead buffer, always-valid addrs, uniform vmcnt).
    {
      char* dst = (char*)Stg[(p + 2) % 3];
      int pn = p + 2;
      if (pn >= NPH) pn -= NPH;
#pragma unroll
      for (int kc = 0; kc < 2; ++kc)
#pragma unroll
        for (int r = 0; r < 2; ++r)
          if (rp[r])
            glld16(rp[r] + (size_t)128 * (2 * pn + kc),
                   dst + kc * CH_B + (w + 12 * r) * 1024);
    }

    // this wave computes only its K-half (kh) of the 128-K phase.
    const char* S = (const char*)Stg[p % 3] + kh * CH_B;
    const int k0 = (2 * p + kh) * 64;
#pragma unroll
    for (int kk = 0; kk < 2; ++kk) {
      const int ko = kk * 32 + q * 8;
      const int xb = (ko * 2) ^ ((lane & 7) << 4);  // swizzled byte off
      const f16x8 hv = *(const f16x8*)&Hr[iw * D3 + k0 + ko];
      f16x8 af[3];
#pragma unroll
      for (int mt = 0; mt < 3; ++mt) {
        const f16x8 s = *(const f16x8*)(S + (jh * 48 + mt * 16 + lm) * 128 + xb) + hv;
        af[mt] = __builtin_elementwise_max(s, zro);
      }
      f16x8 bfv[5];
#pragma unroll
      for (int nt = 0; nt < 5; ++nt)
        bfv[nt] = *(const f16x8*)(S + HT_LDS + (nt * 16 + lm) * 128 + xb);
      __builtin_amdgcn_s_setprio(1);
#pragma unroll
      for (int nt = 0; nt < 5; ++nt)
#pragma unroll
        for (int mt = 0; mt < 3; ++mt)
          acc[mt][nt] = __builtin_amdgcn_mfma_f32_16x16x32_f16(af[mt], bfv[nt], acc[mt][nt], 0, 0, 0);
      __builtin_amdgcn_s_setprio(0);
    }
    // retire all own ds_reads before arriving at the next barrier, so the
    // DMA overwrite of buf[p%3] (issued after barrier p+1) cannot race them.
    asm volatile("s_waitcnt lgkmcnt(0)" ::: "memory");
    __builtin_amdgcn_sched_barrier(0);
  }

  // ---- cross-wave kh reduction through the (now dead) Stg LDS. ----
  // __syncthreads drains this wave's DMAs (incl. wrap prefetches) and
  // barriers, so no stale glld16 can land in Stg after this point.
  __syncthreads();
  float* RED = (float*)&Stg[0][0];  // 6 pairs x 15 slots x 1024 B = 92160 B
  if (w & 1) {
#pragma unroll
    for (int mt = 0; mt < 3; ++mt)
#pragma unroll
      for (int nt = 0; nt < 5; ++nt)
        *(f32x4*)&RED[(((w >> 1) * 15 + mt * 5 + nt) << 8) + lane * 4] = acc[mt][nt];
  }
  __syncthreads();
  if (!(w & 1)) {
    // epilogue: C layout col=lm (c), row=q*4+r (j within 16-tile)
#pragma unroll
    for (int nt = 0; nt < 5; ++nt) {
      const int c = nt * 16 + lm;
      if (c < NC) {
        const float rb = relb[c];
        const int rr = c / 3, tg = c % 3;
#pragma unroll
        for (int mt = 0; mt < 3; ++mt) {
          const f32x4 oth = *(const f32x4*)&RED[(((w >> 1) * 15 + mt * 5 + nt) << 8) + lane * 4];
          const int j0 = jh * 48 + mt * 16 + q * 4;
          float* base = out + ((((size_t)b * TAG + tg) * RR + rr) * SS + i) * SS + j0;
          float4 o;
          o.x = acc[mt][nt][0] + oth[0] + rb;
          o.y = acc[mt][nt][1] + oth[1] + rb;
          o.z = acc[mt][nt][2] + oth[2] + rb;
          o.w = acc[mt][nt][3] + oth[3] + rb;
          *(float4*)base = o;
        }
      }
    }
  }
}

// ---------------------------------------------------------------------------
extern "C" void kernel_launch(void* const* d_in, const int* in_sizes, int n_in,
                              void* d_out, int out_size, void* d_ws, size_t ws_size,
                              hipStream_t stream) {
  const float* enc   = (const float*)d_in[0];  // [8,96,768]
  const float* rel   = (const float*)d_in[1];  // [24,8,768]
  const float* projW = (const float*)d_in[2];  // [1536,2304]
  const float* projb = (const float*)d_in[3];  // [2304]
  const float* relW  = (const float*)d_in[4];  // [2304,72]
  const float* relb  = (const float*)d_in[5];  // [72]
  float* out = (float*)d_out;                  // [8,3,24,96,96]

  uint16_t* Hh16 = (uint16_t*)d_ws;                       // 768*2304 f16 (+512 slack)
  uint16_t* Htf  = Hh16 + (size_t)DD * D3 + 512;          // 768*2304 f16
  uint16_t* Wb   = Htf + (size_t)DD * D3;                 // 96*2304 f16 (80 used)
  uint16_t* Tp   = Wb + (size_t)96 * D3;                  // 2304*1536 bf16
  uint16_t* Ab   = Tp + (size_t)D3 * 2 * DD;              // 768*768 bf16
  float* Pst = (float*)(Ab + (size_t)DD * DD);            // 8*8*96 f32
  float* SG = Pst + (size_t)BB * RSEQ * SS;               // 8*8*104 f32

  hipMemsetAsync(SG, 0, (size_t)BB * RSEQ * 104 * sizeof(float), stream);
  k_prep0<<<1028, 256, 0, stream>>>(relW, Wb, projW, Tp, enc, rel, SG);
  k_refS<<<BB, 64, 0, stream>>>(SG, Pst);
  k_refB<<<96, 256, 0, stream>>>(enc, rel, Pst, Ab);
  k_proj<<<dim3(6, 72), 256, 0, stream>>>(Ab, Tp, projb, Hh16, Htf);
  k_pairs<<<256, 768, 0, stream>>>(Hh16, Htf, Wb, relb, out);
}

// Round 14
// 181.538 us; speedup vs baseline: 1.1076x; 1.0306x over previous
//
#include <hip/hip_runtime.h>
#include <hip/hip_bf16.h>
#include <math.h>
#include <stdint.h>
#include <string.h>

#define BB 8
#define SS 96
#define DD 768
#define RR 24
#define RSEQ 8
#define TAG 3
#define D3 2304   // 3*D
#define NC 72     // R*TAG

typedef __attribute__((ext_vector_type(8))) short bf16x8;
typedef __attribute__((ext_vector_type(4))) float f32x4;
typedef _Float16 f16x8 __attribute__((ext_vector_type(8)));
typedef _Float16 f16x2 __attribute__((ext_vector_type(2)));

// async global->LDS, 16 B/lane; LDS dest = wave-uniform base + lane*16.
typedef __attribute__((address_space(3))) uint8_t lds_u8;
typedef const __attribute__((address_space(1))) uint8_t glb_u8;
static __device__ __forceinline__ void glld16(const void* g, void* l) {
  __builtin_amdgcn_global_load_lds((glb_u8*)g, (lds_u8*)l, 16, 0, 0);
}

#define VMW(N) asm volatile("s_waitcnt vmcnt(" #N ")" ::: "memory")

// round-half-up f32 pair -> packed bf16x2: add,add,v_perm = 3 VALU.
static __device__ inline uint32_t pkrhu(float lo, float hi) {
  uint32_t a, b;
  memcpy(&a, &lo, 4);
  memcpy(&b, &hi, 4);
  return __builtin_amdgcn_perm(b + 0x8000u, a + 0x8000u, 0x07060302u);
}
static __device__ inline uint32_t pkrne(float lo, float hi) {
  uint32_t a, b;
  memcpy(&a, &lo, 4);
  memcpy(&b, &hi, 4);
  a += 0x7FFFu + ((a >> 16) & 1u);
  b += 0x7FFFu + ((b >> 16) & 1u);
  return (a >> 16) | (b & 0xFFFF0000u);
}
// f32 pair -> packed f16x2 (v_cvt_f16_f32 x2 + pack)
static __device__ inline uint32_t pkf16(float lo, float hi) {
  union { f16x2 h; uint32_t u; } r;
  r.h[0] = (_Float16)lo;
  r.h[1] = (_Float16)hi;
  return r.u;
}
static __device__ inline uint16_t f16b(float v) {
  union { _Float16 h; uint16_t u; } r;
  r.h = (_Float16)v;
  return r.u;
}

// ---------------------------------------------------------------------------
// Kernel 0 (fused prep): blocks 0..35 = prepW (rel_W^T -> f16), 36..899 =
// proj_W transpose (bf16, feeds k_proj MFMA), 900..1027 = S0/G k-split
// partial dots (atomicAdd into pre-zeroed SG).
// ---------------------------------------------------------------------------
__global__ __launch_bounds__(256) void k_prep0(const float* __restrict__ relW,
                                               uint16_t* __restrict__ Wb,
                                               const float* __restrict__ projW,
                                               uint16_t* __restrict__ Tp,
                                               const float* __restrict__ enc,
                                               const float* __restrict__ rel,
                                               float* __restrict__ SG) {
  __shared__ __align__(16) char smem[24704];
  const int blk = blockIdx.x;
  const int t = threadIdx.x;

  if (blk < 36) {
    // ---- Wb[96][2304] f16 = rel_W^T (rows 72..79 zero; 80..95 untouched) ----
    float* tile = (float*)smem;  // 64*72 f32
    const int k0 = blk * 64;
    const float* src = relW + (size_t)k0 * NC;
    for (int e = t; e < 64 * NC / 4; e += 256) ((float4*)tile)[e] = ((const float4*)src)[e];
    __syncthreads();
    for (int u = t; u < 80 * 16; u += 256) {
      const int n = u >> 4, kq = (u & 15) * 4;
      uint2 w = {0u, 0u};
      if (n < NC) {
        w.x = pkf16(tile[(kq + 0) * NC + n], tile[(kq + 1) * NC + n]);
        w.y = pkf16(tile[(kq + 2) * NC + n], tile[(kq + 3) * NC + n]);
      }
      *(uint2*)&Wb[(size_t)n * D3 + k0 + kq] = w;
    }
  } else if (blk < 900) {
    // ---- Tp[2304][1536] bf16 = proj_W^T, 64x64 tile ----
    const int bx = blk - 36;
    float (*tile)[65] = (float(*)[65])smem;
    const int c0 = (bx % 36) * 64;
    const int r0 = (bx / 36) * 64;
    {
      const int tr = t >> 4;
      const int tc4 = (t & 15) * 4;
#pragma unroll
      for (int p = 0; p < 4; ++p) {
        const int r = tr + p * 16;
        const float4 v = *(const float4*)&projW[(size_t)(r0 + r) * D3 + c0 + tc4];
        tile[r][tc4 + 0] = v.x;
        tile[r][tc4 + 1] = v.y;
        tile[r][tc4 + 2] = v.z;
        tile[r][tc4 + 3] = v.w;
      }
    }
    __syncthreads();
    {
      const int cc = t >> 4;
      const int rr4 = (t & 15) * 4;
#pragma unroll
      for (int p = 0; p < 4; ++p) {
        const int c = cc + p * 16;
        uint2 w;
        w.x = pkrne(tile[rr4 + 0][c], tile[rr4 + 1][c]);
        w.y = pkrne(tile[rr4 + 2][c], tile[rr4 + 3][c]);
        *(uint2*)&Tp[(size_t)(c0 + c) * (2 * DD) + r0 + rr4] = w;
      }
    }
  } else {
    // ---- S0/G partial: sample b, d-chunk [d0, d0+48). ----
    const int idx = blk - 900;
    const int b = idx >> 4;
    const int d0 = (idx & 15) * 48;
    float (*AsF)[48] = (float(*)[48])smem;  // 8 x 48 f32 = 1.5 KB

    if (t < 96) {
      const int r = t / 12, q4 = (t % 12) * 4;
      *(float4*)&AsF[r][q4] = *(const float4*)&rel[((size_t)b * RSEQ + r) * DD + d0 + q4];
    }
    __syncthreads();

    for (int e = t; e < RSEQ * (SS + RSEQ); e += 256) {
      const int r = e & 7, s = e >> 3;
      const float* row = (s < SS) ? (enc + ((size_t)b * SS + s) * DD + d0) : &AsF[s - SS][0];
      float a0 = 0.f, a1 = 0.f, a2 = 0.f, a3 = 0.f;
#pragma unroll
      for (int d = 0; d < 48; d += 4) {
        const float4 rv = *(const float4*)&row[d];
        a0 += AsF[r][d + 0] * rv.x;
        a1 += AsF[r][d + 1] * rv.y;
        a2 += AsF[r][d + 2] * rv.z;
        a3 += AsF[r][d + 3] * rv.w;
      }
      atomicAdd(&SG[((size_t)b * RSEQ + r) * 104 + s], (a0 + a1) + (a2 + a3));
    }
  }
}

// ---------------------------------------------------------------------------
// Kernel 1a: refine serial core (REVERTED to the round-8 proven 256-thread
// LDS version — the register-resident rewrites v2-v6 all lost to the
// allocator's rematerialization/spill behavior; best measured was 48us vs
// this version's ~15us). 24 collapsed attention steps on precomputed S0/G.
// Writes P[8][96]. grid 8 x 256.
// ---------------------------------------------------------------------------
__global__ __launch_bounds__(256) void k_refS(const float* __restrict__ SG,
                                              float* __restrict__ Pst) {
  const int b = blockIdx.x;
  const int t = threadIdx.x;
  __shared__ float S0[RSEQ][SS];
  __shared__ float G[RSEQ][RSEQ];
  __shared__ float P[RSEQ][SS];
  __shared__ float sc[RSEQ][SS];
  const float scale = 0.036084391824351613f;  // 1/sqrt(768)

  for (int e = t; e < RSEQ * 104; e += 256) {
    const int r = e / 104, c = e % 104;
    const float v = SG[(size_t)b * RSEQ * 104 + e];
    if (c < SS) S0[r][c] = v;
    else G[r][c - SS] = v;
  }
  for (int e = t; e < RSEQ * SS; e += 256) ((float*)P)[e] = 0.f;
  __syncthreads();

  const int wave = t >> 6, lane = t & 63;
  for (int step = 0; step < RR; ++step) {
    for (int e = t; e < RSEQ * SS; e += 256) {
      const int r = e / SS, s = e % SS;
      float acc = S0[r][s];
#pragma unroll
      for (int r2 = 0; r2 < RSEQ; ++r2) acc += G[r][r2] * P[r2][s];
      sc[r][s] = acc * scale;
    }
    __syncthreads();
#pragma unroll
    for (int rr = 0; rr < 2; ++rr) {
      const int r = wave * 2 + rr;
      const float m1 = sc[r][lane];
      const float m2 = (lane < 32) ? sc[r][lane + 64] : -1e30f;
      float mx = fmaxf(m1, m2);
#pragma unroll
      for (int o = 32; o > 0; o >>= 1) mx = fmaxf(mx, __shfl_xor(mx, o, 64));
      const float e1 = __expf(m1 - mx);
      const float e2 = (lane < 32) ? __expf(m2 - mx) : 0.f;
      float sm = e1 + e2;
#pragma unroll
      for (int o = 32; o > 0; o >>= 1) sm += __shfl_xor(sm, o, 64);
      const float inv = 1.f / sm;
      P[r][lane] += e1 * inv;
      if (lane < 32) P[r][lane + 64] += e2 * inv;
    }
    __syncthreads();
  }

  for (int e = t; e < RSEQ * SS; e += 256) Pst[(size_t)b * RSEQ * SS + e] = ((float*)P)[e];
}

// ---------------------------------------------------------------------------
// Kernel 1b: refine epilogue: enc' bf16 = enc + P^T @ A. grid 96 (8 rows/blk).
// ---------------------------------------------------------------------------
__global__ __launch_bounds__(256) void k_refB(const float* __restrict__ enc,
                                              const float* __restrict__ rel,
                                              const float* __restrict__ Pst,
                                              uint16_t* __restrict__ encRb) {
  const int blk = blockIdx.x;
  const int b = blk / 12;
  const int s0 = (blk % 12) * 8;
  const int t = threadIdx.x;
  __shared__ float As[RSEQ][DD + 4];
  __shared__ float Pl[RSEQ][8];

  const float* Ag = rel + (size_t)b * RSEQ * DD;
  for (int e = t; e < RSEQ * DD / 4; e += 256) {
    const int r = (e * 4) / DD, d = (e * 4) % DD;
    *(float4*)&As[r][d] = *(const float4*)&Ag[e * 4];
  }
  if (t < RSEQ * 8) {
    const int r = t >> 3, sl = t & 7;
    Pl[r][sl] = Pst[(size_t)b * RSEQ * SS + r * SS + s0 + sl];
  }
  __syncthreads();

  const float* Eb = enc + ((size_t)b * SS + s0) * DD;
  uint16_t* Ob = encRb + ((size_t)b * SS + s0) * DD;
  for (int e = t; e < 8 * DD / 4; e += 256) {
    const int sl = (e * 4) / DD, d = (e * 4) % DD;
    float4 v = ((const float4*)Eb)[e];
#pragma unroll
    for (int r = 0; r < RSEQ; ++r) {
      const float p = Pl[r][sl];
      v.x += p * As[r][d + 0];
      v.y += p * As[r][d + 1];
      v.z += p * As[r][d + 2];
      v.w += p * As[r][d + 3];
    }
    uint2 w;
    w.x = pkrhu(v.x, v.y);
    w.y = pkrhu(v.z, v.w);
    *(uint2*)&Ob[e * 4] = w;
  }
}

// ---------------------------------------------------------------------------
// Kernel 2 v2: projection GEMM — 128x64 tiles: reads/MFMA 0.75, 432 blocks.
// glld16 2-barrier schedule. LDS 27648 B -> 4 blocks/CU. grid (6,72).
// ---------------------------------------------------------------------------
__global__ __launch_bounds__(256, 4) void k_proj(const uint16_t* __restrict__ Ab,
                                                 const uint16_t* __restrict__ Bt,
                                                 const float* __restrict__ pb,
                                                 uint16_t* __restrict__ Hh16,
                                                 uint16_t* __restrict__ Htf) {
  const int m0 = blockIdx.x * 128;
  const int gn0 = blockIdx.y * 64;
  const bool isH = gn0 < D3;               // uniform per block
  const int n0 = isH ? gn0 : gn0 - D3;
  const int halfk = isH ? 0 : DD;
  const int t = threadIdx.x, w = t >> 6, lane = t & 63;
  const int wm = w >> 1, wn = w & 1;
  const int lm = lane & 15, q = lane >> 4;

  __shared__ __align__(16) uint16_t As[128 * 72];  // 18432 B (18 issues)
  __shared__ __align__(16) uint16_t Bs[64 * 72];   //  9216 B (9 issues)

  const char* rp[7];
  char* lp[7];
#pragma unroll
  for (int r = 0; r < 7; ++r) {
    const int idx = w + 4 * r;
    rp[r] = nullptr;
    lp[r] = nullptr;
    if (idx < 27) {
      const int ii = (idx < 18) ? idx : idx - 18;
      const int beta = ii * 1024 + lane * 16;
      const int elem = beta >> 1;
      const int row = elem / 72;
      int o = elem - row * 72;
      if (o >= 64) o = 0;  // pad lanes: safe addr, land in LDS row pad
      if (idx < 18) {
        rp[r] = (const char*)(Ab + (size_t)(m0 + row) * DD + o);
        lp[r] = (char*)As + ii * 1024;
      } else {
        rp[r] = (const char*)(Bt + (size_t)(n0 + row) * (2 * DD) + halfk + o);
        lp[r] = (char*)Bs + ii * 1024;
      }
    }
  }

  f32x4 acc[4][2];
#pragma unroll
  for (int a = 0; a < 4; ++a)
#pragma unroll
    for (int c = 0; c < 2; ++c) acc[a][c] = (f32x4){0.f, 0.f, 0.f, 0.f};

  for (int k0 = 0; k0 < DD; k0 += 64) {
    __syncthreads();
#pragma unroll
    for (int r = 0; r < 7; ++r)
      if (rp[r]) glld16(rp[r] + 2 * k0, lp[r]);
    __syncthreads();
#pragma unroll
    for (int kk = 0; kk < 2; ++kk) {
      const int ko = kk * 32 + q * 8;
      bf16x8 af[4], bf[2];
#pragma unroll
      for (int mt = 0; mt < 4; ++mt)
        af[mt] = *(const bf16x8*)&As[(wm * 64 + mt * 16 + lm) * 72 + ko];
#pragma unroll
      for (int nt = 0; nt < 2; ++nt)
        bf[nt] = *(const bf16x8*)&Bs[(wn * 32 + nt * 16 + lm) * 72 + ko];
#pragma unroll
      for (int nt = 0; nt < 2; ++nt)
#pragma unroll
        for (int mt = 0; mt < 4; ++mt)
          acc[mt][nt] = __builtin_amdgcn_mfma_f32_16x16x32_bf16(af[mt], bf[nt], acc[mt][nt], 0, 0, 0);
    }
  }

#pragma unroll
  for (int nt = 0; nt < 2; ++nt) {
    const int ncol = n0 + wn * 32 + nt * 16 + lm;
    const int mrow = m0 + wm * 64 + q * 4;
    uint16_t* dst = isH ? Hh16 : Htf;
    const float bias = isH ? pb[ncol] : 0.f;
#pragma unroll
    for (int mt = 0; mt < 4; ++mt)
#pragma unroll
      for (int r = 0; r < 4; ++r)
        dst[(size_t)(mrow + mt * 16 + r) * D3 + ncol] = f16b(acc[mt][nt][r] + bias);
  }
}

// ---------------------------------------------------------------------------
// Kernel 3: pairwise GEMM v14 (frozen) — 12 waves = (iw x jh x kh); wave does
// full 48x80 tile of its i for its K=64 half of each 128-K phase; wave pairs
// reduce acc at the end through dead Stg. 3 pair-bufs, issue-after-barrier,
// counted vmcnt 4/2, XOR-swizzle, wrap prefetch, LDS 150528 -> 1 block/CU.
// grid 256, 768 threads.
// ---------------------------------------------------------------------------
#define HT_LDS 12288                     // 96 rows x 128 B
#define CH_B 22528                       // one chunk: 22 issues x 1024
#define NISS 22
#define NKC 36                           // K chunks of 64
#define NPH 18                           // phases of 2 chunks

__global__ __launch_bounds__(768, 1) void k_pairs(const uint16_t* __restrict__ Hh,
                                                  const uint16_t* __restrict__ Htb,
                                                  const uint16_t* __restrict__ Wb,
                                                  const float* __restrict__ relb,
                                                  float* __restrict__ out) {
  const int blk = blockIdx.x;
  const int b = blk >> 5, ii = blk & 31;
  const int t = threadIdx.x;
  const int w = t >> 6, lane = t & 63;
  const int lm = lane & 15, q = lane >> 4;
  const int iw = w >> 2;            // which of the 3 i's
  const int jh = (w >> 1) & 1;      // j-half (48 rows)
  const int kh = w & 1;             // K-half of each phase
  const int i = ii * 3 + iw;

  __shared__ __align__(16) uint16_t Hr[7680];             // 15360 B
  __shared__ __align__(16) uint16_t Stg[3][CH_B];         // 3 pair-bufs x 45056 B

  // ---- one-time: stage the 3 Hh rows (linear; issue idx 13 runs 512 B past
  //      the 3 rows — covered by Hh's slack) ----
  {
    const char* hh = (const char*)(Hh + ((size_t)b * SS + ii * 3) * D3);
#pragma unroll
    for (int r = 0; r < 2; ++r) {
      const int idx = w + 12 * r;
      if (idx < 14) glld16(hh + idx * 1024 + lane * 16, (char*)Hr + idx * 1024);
    }
  }

  // ---- per-lane k0-invariant inverse-swizzled source pointers.
  //      LDS byte beta holds elem (real>>1) of its row, real = off^((row&7)<<4).
  //      Issues per wave per chunk: w0-9: 2, w10-11: 1.
  const char* rp[2];
#pragma unroll
  for (int r = 0; r < 2; ++r) {
    const int idx = w + 12 * r;
    rp[r] = nullptr;
    if (idx < NISS) {
      const int beta = idx * 1024 + lane * 16;
      if (beta < HT_LDS) {
        const int row = beta >> 7;
        const int real = (beta & 127) ^ ((row & 7) << 4);
        rp[r] = (const char*)(Htb + ((size_t)b * SS + row) * D3 + (real >> 1));
      } else {
        const int bb = beta - HT_LDS;
        const int row = bb >> 7;
        const int real = (bb & 127) ^ ((row & 7) << 4);
        rp[r] = (const char*)(Wb + (size_t)row * D3 + (real >> 1));
      }
    }
  }

  // ---- prologue: stage pairs 0 and 1 ----
#pragma unroll
  for (int pp = 0; pp < 2; ++pp)
#pragma unroll
    for (int kc = 0; kc < 2; ++kc)
#pragma unroll
      for (int r = 0; r < 2; ++r)
        if (rp[r])
          glld16(rp[r] + (size_t)128 * (2 * pp + kc),
                 (char*)Stg[pp] + kc * CH_B + (w + 12 * r) * 1024);

  f32x4 acc[3][5];
#pragma unroll
  for (int mt = 0; mt < 3; ++mt)
#pragma unroll
    for (int nt = 0; nt < 5; ++nt) acc[mt][nt] = (f32x4){0.f, 0.f, 0.f, 0.f};

  const f16x8 zro = {0, 0, 0, 0, 0, 0, 0, 0};

  for (int p = 0; p < NPH; ++p) {
    // drain pair-p loads (and Hr on phase 0); keep pair p+1 in flight.
    if (w < 10) VMW(4); else VMW(2);
    __builtin_amdgcn_s_barrier();   // all waves' pair-p loads visible
    __builtin_amdgcn_sched_barrier(0);

    // issue pair p+2 into buf[(p+2)%3] — overlaps this phase's compute.
    // Past the end it WRAPS (dead buffer, always-valid addrs, uniform vmcnt).
    {
      char* dst = (char*)Stg[(p + 2) % 3];
      int pn = p + 2;
      if (pn >= NPH) pn -= NPH;
#pragma unroll
      for (int kc = 0; kc < 2; ++kc)
#pragma unroll
        for (int r = 0; r < 2; ++r)
          if (rp[r])
            glld16(rp[r] + (size_t)128 * (2 * pn + kc),
                   dst + kc * CH_B + (w + 12 * r) * 1024);
    }

    // this wave computes only its K-half (kh) of the 128-K phase.
    const char* S = (const char*)Stg[p % 3] + kh * CH_B;
    const int k0 = (2 * p + kh) * 64;
#pragma unroll
    for (int kk = 0; kk < 2; ++kk) {
      const int ko = kk * 32 + q * 8;
      const int xb = (ko * 2) ^ ((lane & 7) << 4);  // swizzled byte off
      const f16x8 hv = *(const f16x8*)&Hr[iw * D3 + k0 + ko];
      f16x8 af[3];
#pragma unroll
      for (int mt = 0; mt < 3; ++mt) {
        const f16x8 s = *(const f16x8*)(S + (jh * 48 + mt * 16 + lm) * 128 + xb) + hv;
        af[mt] = __builtin_elementwise_max(s, zro);
      }
      f16x8 bfv[5];
#pragma unroll
      for (int nt = 0; nt < 5; ++nt)
        bfv[nt] = *(const f16x8*)(S + HT_LDS + (nt * 16 + lm) * 128 + xb);
      __builtin_amdgcn_s_setprio(1);
#pragma unroll
      for (int nt = 0; nt < 5; ++nt)
#pragma unroll
        for (int mt = 0; mt < 3; ++mt)
          acc[mt][nt] = __builtin_amdgcn_mfma_f32_16x16x32_f16(af[mt], bfv[nt], acc[mt][nt], 0, 0, 0);
      __builtin_amdgcn_s_setprio(0);
    }
    // retire all own ds_reads before arriving at the next barrier, so the
    // DMA overwrite of buf[p%3] (issued after barrier p+1) cannot race them.
    asm volatile("s_waitcnt lgkmcnt(0)" ::: "memory");
    __builtin_amdgcn_sched_barrier(0);
  }

  // ---- cross-wave kh reduction through the (now dead) Stg LDS. ----
  // __syncthreads drains this wave's DMAs (incl. wrap prefetches) and
  // barriers, so no stale glld16 can land in Stg after this point.
  __syncthreads();
  float* RED = (float*)&Stg[0][0];  // 6 pairs x 15 slots x 1024 B = 92160 B
  if (w & 1) {
#pragma unroll
    for (int mt = 0; mt < 3; ++mt)
#pragma unroll
      for (int nt = 0; nt < 5; ++nt)
        *(f32x4*)&RED[(((w >> 1) * 15 + mt * 5 + nt) << 8) + lane * 4] = acc[mt][nt];
  }
  __syncthreads();
  if (!(w & 1)) {
    // epilogue: C layout col=lm (c), row=q*4+r (j within 16-tile)
#pragma unroll
    for (int nt = 0; nt < 5; ++nt) {
      const int c = nt * 16 + lm;
      if (c < NC) {
        const float rb = relb[c];
        const int rr = c / 3, tg = c % 3;
#pragma unroll
        for (int mt = 0; mt < 3; ++mt) {
          const f32x4 oth = *(const f32x4*)&RED[(((w >> 1) * 15 + mt * 5 + nt) << 8) + lane * 4];
          const int j0 = jh * 48 + mt * 16 + q * 4;
          float* base = out + ((((size_t)b * TAG + tg) * RR + rr) * SS + i) * SS + j0;
          float4 o;
          o.x = acc[mt][nt][0] + oth[0] + rb;
          o.y = acc[mt][nt][1] + oth[1] + rb;
          o.z = acc[mt][nt][2] + oth[2] + rb;
          o.w = acc[mt][nt][3] + oth[3] + rb;
          *(float4*)base = o;
        }
      }
    }
  }
}

// ---------------------------------------------------------------------------
extern "C" void kernel_launch(void* const* d_in, const int* in_sizes, int n_in,
                              void* d_out, int out_size, void* d_ws, size_t ws_size,
                              hipStream_t stream) {
  const float* enc   = (const float*)d_in[0];  // [8,96,768]
  const float* rel   = (const float*)d_in[1];  // [24,8,768]
  const float* projW = (const float*)d_in[2];  // [1536,2304]
  const float* projb = (const float*)d_in[3];  // [2304]
  const float* relW  = (const float*)d_in[4];  // [2304,72]
  const float* relb  = (const float*)d_in[5];  // [72]
  float* out = (float*)d_out;                  // [8,3,24,96,96]

  uint16_t* Hh16 = (uint16_t*)d_ws;                       // 768*2304 f16 (+512 slack)
  uint16_t* Htf  = Hh16 + (size_t)DD * D3 + 512;          // 768*2304 f16
  uint16_t* Wb   = Htf + (size_t)DD * D3;                 // 96*2304 f16 (80 used)
  uint16_t* Tp   = Wb + (size_t)96 * D3;                  // 2304*1536 bf16
  uint16_t* Ab   = Tp + (size_t)D3 * 2 * DD;              // 768*768 bf16
  float* Pst = (float*)(Ab + (size_t)DD * DD);            // 8*8*96 f32
  float* SG = Pst + (size_t)BB * RSEQ * SS;               // 8*8*104 f32

  hipMemsetAsync(SG, 0, (size_t)BB * RSEQ * 104 * sizeof(float), stream);
  k_prep0<<<1028, 256, 0, stream>>>(relW, Wb, projW, Tp, enc, rel, SG);
  k_refS<<<BB, 256, 0, stream>>>(SG, Pst);
  k_refB<<<96, 256, 0, stream>>>(enc, rel, Pst, Ab);
  k_proj<<<dim3(6, 72), 256, 0, stream>>>(Ab, Tp, projb, Hh16, Htf);
  k_pairs<<<256, 768, 0, stream>>>(Hh16, Htf, Wb, relb, out);
}